// Round 17
// baseline (183.019 us; speedup 1.0000x reference)
//
#include <hip/hip_runtime.h>
#include <hip/hip_fp16.h>
#include <math.h>

#define TID threadIdx.x

typedef ushort u16x8 __attribute__((ext_vector_type(8)));
typedef unsigned char uchar;

static constexpr int NN = 20000;
static constexpr int NE = 640000;
static constexpr int NT = 1000000;
static constexpr int C = 128;
static constexpr int E = 64;
static constexpr int LUTN = 4104;     // 4097 live rows + zero padding
static constexpr int NBKT = 313;      // buckets of 64 nodes (313*64 = 20032)
static constexpr int NB2 = 512;       // sort blocks
static constexpr int CHE2 = 1250;     // NE / 512
static constexpr int CHT2 = 1954;     // ceil(NT / 512)
static constexpr int G_GEMM = (NN + 15) / 16;    // 1250
static constexpr int G_LUT = (LUTN + 7) / 8 + 1; // 514 (last = spLut)
static constexpr int G_SCAN = (2 * NBKT + 3) / 4; // 157
static constexpr int G_PACK = LUTN / 8;           // 513
static constexpr int G_CONS_E = 1024;
static constexpr int G_CONS_T = 1024;
static constexpr float CUT = 5.0f;
static constexpr float LN2 = 0.69314718055994530942f;

__device__ __forceinline__ float ssp(float x) {
    return fmaxf(x, 0.0f) + __logf(1.0f + __expf(-fabsf(x))) - LN2;
}

__device__ __forceinline__ ushort f2bf(float x) {
    uint u = __float_as_uint(x);
    return (ushort)((u + 0x7FFFu + ((u >> 16) & 1u)) >> 16);
}

__device__ __forceinline__ float bf2f(ushort u) {
    return __uint_as_float((uint)u << 16);
}

__device__ __forceinline__ float h2f(uint bits) {
    return __half2float(__ushort_as_half((ushort)(bits & 0xFFFFu)));
}

// ---- Fused front-end: [0,G_GEMM) gemm16b | [G_GEMM,+513) lutB | +513 spLut | rest bcount ----
__global__ __launch_bounds__(256) void k_front(const float* __restrict__ features,
                                               const float* __restrict__ W_pre,
                                               ushort* __restrict__ hB,
                                               const float* __restrict__ W2b1,
                                               const float* __restrict__ W2b2,
                                               ushort* __restrict__ lutB,
                                               float2* __restrict__ spLut,
                                               const int* __restrict__ nl0,
                                               const int* __restrict__ tidx,
                                               uchar* __restrict__ cntE,
                                               uchar* __restrict__ cntT) {
    __shared__ __align__(16) char smem[53248];
    const int bid = blockIdx.x;
    if (bid < G_GEMM) {
        ushort* wB = (ushort*)smem;                       // 32 KB
        float (*aL)[132] = (float(*)[132])(smem + 32768); // 8.25 KB
        for (int i = TID; i < C * C / 4; i += 256) {
            float4 w4 = ((const float4*)W_pre)[i];
            ushort4 u = {f2bf(w4.x), f2bf(w4.y), f2bf(w4.z), f2bf(w4.w)};
            ((ushort4*)wB)[i] = u;
        }
        const int base = bid * 16;
        for (int i = TID; i < 512; i += 256) {
            int r = base + (i >> 5);
            float4 v = (r < NN) ? ((const float4*)features)[(size_t)r * 32 + (i & 31)]
                                : (float4){0.f, 0.f, 0.f, 0.f};
            *(float4*)&aL[i >> 5][(i & 31) << 2] = v;
        }
        __syncthreads();
        const int rg = TID >> 4;
        const int c8 = (TID & 15) << 3;
        float acc[8] = {0.f, 0.f, 0.f, 0.f, 0.f, 0.f, 0.f, 0.f};
        #pragma unroll 8
        for (int k = 0; k < C; ++k) {
            float a = aL[rg][k];
            u16x8 wv = *(const u16x8*)&wB[k * C + c8];
            #pragma unroll
            for (int j = 0; j < 8; ++j) acc[j] = fmaf(a, bf2f(wv[j]), acc[j]);
        }
        int r = base + rg;
        if (r < NN) {
            u16x8 u;
            #pragma unroll
            for (int j = 0; j < 8; ++j) u[j] = f2bf(acc[j]);
            *(u16x8*)&hB[(size_t)r * C + c8] = u;
        }
        return;
    }
    if (bid < G_GEMM + G_LUT) {
        const int lb = bid - G_GEMM;
        if (lb == G_LUT - 1) {
            for (int e = TID; e < 512; e += 256) {
                float t0 = (float)e * (1.0f / 32.0f);
                float t1 = (float)(e + 1) * (1.0f / 32.0f);
                float v0 = log1pf(__expf(-t0));
                float v1 = log1pf(__expf(-t1));
                spLut[e] = make_float2(v0, v1 - v0);
            }
            return;
        }
        float* w1 = (float*)smem;                         // 16 KB
        float* w2 = (float*)(smem + 16384);               // 32 KB
        float (*rbL)[E] = (float(*)[E])(smem + 49152);    // 2 KB
        float (*hid)[E] = (float(*)[E])(smem + 51200);    // 2 KB
        for (int i = TID; i < E * E; i += 256) w1[i] = W2b1[i];
        for (int i = TID; i < E * C; i += 256) w2[i] = W2b2[i];
        const int jj = TID & 63;
        const int esA = TID >> 6;
        const int eg = TID >> 5;
        const int c4 = (TID & 31) << 2;
        const float gamma = 81.92f;
        const float cstep = CUT / 63.0f;
        const float delta = CUT / 4096.0f;
        const int base = lb * 8;
        __syncthreads();
        #pragma unroll
        for (int s = 0; s < 2; ++s) {
            int es = esA + 4 * s;
            float d = (float)(base + es) * delta;
            float cv = (d < CUT) ? 0.5f * (1.0f + __cosf((float)M_PI * d / CUT)) : 0.0f;
            float dd = d - (float)jj * cstep;
            rbL[es][jj] = __expf(-gamma * dd * dd) * cv;
        }
        __syncthreads();
        #pragma unroll
        for (int s = 0; s < 2; ++s) {
            int es = esA + 4 * s;
            float a = 0.f;
            #pragma unroll 16
            for (int k = 0; k < E; ++k)
                a = fmaf(rbL[es][k], w1[k * E + jj], a);
            hid[es][jj] = ssp(a);
        }
        __syncthreads();
        float4 o = {0.f, 0.f, 0.f, 0.f};
        #pragma unroll
        for (int j = 0; j < E; ++j) {
            float t = hid[eg][j];
            const float4 w4 = *(const float4*)&w2[j * C + c4];
            o.x = fmaf(t, w4.x, o.x);
            o.y = fmaf(t, w4.y, o.y);
            o.z = fmaf(t, w4.z, o.z);
            o.w = fmaf(t, w4.w, o.w);
        }
        int row = base + eg;
        if (row < LUTN) {
            ushort4 u = {f2bf(o.x), f2bf(o.y), f2bf(o.z), f2bf(o.w)};
            *(ushort4*)&lutB[(size_t)row * C + c4] = u;
        }
        return;
    }
    // ---- bcount ----
    {
        int* h = (int*)smem;
        const int b = bid - G_GEMM - G_LUT;
        for (int i = TID; i < NBKT; i += 256) h[i] = 0;
        __syncthreads();
        const int e0 = b * CHE2, e1 = min(e0 + CHE2, NE);
        for (int i = e0 + TID; i < e1; i += 256) atomicAdd(&h[nl0[i] >> 6], 1);
        __syncthreads();
        for (int i = TID; i < NBKT; i += 256) { cntE[(size_t)i * NB2 + b] = (uchar)h[i]; h[i] = 0; }
        __syncthreads();
        const int t0 = b * CHT2, t1 = min(t0 + CHT2, NT);
        for (int i = t0 + TID; i < t1; i += 256) atomicAdd(&h[tidx[3 * i + 1] >> 6], 1);
        __syncthreads();
        for (int i = TID; i < NBKT; i += 256) cntT[(size_t)i * NB2 + b] = (uchar)h[i];
    }
}

// Mid: [0,G_SCAN) per-bucket scans | [G_SCAN, +G_PACK) pack lutB -> lutP (value,delta) pairs.
__global__ __launch_bounds__(256) void k_mid(const uchar* __restrict__ cE,
                                             const uchar* __restrict__ cT,
                                             ushort* __restrict__ baseE,
                                             ushort* __restrict__ baseT,
                                             int* __restrict__ totEb,
                                             int* __restrict__ totTb,
                                             const ushort* __restrict__ lutB,
                                             ushort* __restrict__ lutP) {
    if (blockIdx.x >= G_SCAN) {
        // pack: pair-row idx, column-pair cp -> {v_2cp, d_2cp, v_2cp+1, d_2cp+1}
        const int pb = blockIdx.x - G_SCAN;
        for (int i = TID; i < 8 * 64; i += 256) {
            int idx = pb * 8 + (i >> 6);
            int cp = i & 63;
            int idx1 = min(idx + 1, LUTN - 1);
            ushort2 v = *(const ushort2*)&lutB[(size_t)idx * C + cp * 2];
            ushort2 n = *(const ushort2*)&lutB[(size_t)idx1 * C + cp * 2];
            ushort4 o;
            o.x = v.x;
            o.y = f2bf(bf2f(n.x) - bf2f(v.x));
            o.z = v.y;
            o.w = f2bf(bf2f(n.y) - bf2f(v.y));
            *(ushort4*)&lutP[((size_t)idx * 64 + cp) * 4] = o;
        }
        return;
    }
    const int lane = TID & 63;
    const int wv = TID >> 6;
    int task = blockIdx.x * 4 + wv;
    if (task >= 2 * NBKT) return;
    const bool isE = task < NBKT;
    const int k = isE ? task : task - NBKT;
    const uchar* src = isE ? cE : cT;
    ushort* dst = isE ? baseE : baseT;
    int* dT = isE ? totEb : totTb;
    int v[8], pre[8], s = 0;
    #pragma unroll
    for (int j = 0; j < 8; ++j) {
        v[j] = src[(size_t)k * NB2 + lane * 8 + j];
        pre[j] = s;
        s += v[j];
    }
    int incl = s;
    #pragma unroll
    for (int off = 1; off < 64; off <<= 1) {
        int t = __shfl_up(incl, off, 64);
        if (lane >= off) incl += t;
    }
    int excl = incl - s;
    #pragma unroll
    for (int j = 0; j < 8; ++j)
        dst[(size_t)k * NB2 + lane * 8 + j] = (ushort)(excl + pre[j]);
    if (lane == 63) dT[k] = incl;
}

// Phase-1 placement into bucket regions; bucket starts computed inline (1 wave each).
__global__ __launch_bounds__(256) void k_bplace(const int* __restrict__ nl0,
                                                const int* __restrict__ nl1,
                                                const float* __restrict__ dist,
                                                const int* __restrict__ tidx,
                                                const float* __restrict__ angles,
                                                const float* __restrict__ rij,
                                                const float* __restrict__ rik,
                                                const ushort* __restrict__ baseE,
                                                const ushort* __restrict__ baseT,
                                                const int* __restrict__ totEb,
                                                const int* __restrict__ totTb,
                                                int2* __restrict__ eT,
                                                int2* __restrict__ tT) {
    __shared__ int cur[NBKT];
    __shared__ int bksEs[NBKT];
    __shared__ int bksTs[NBKT];
    const int lane = TID & 63;
    const int wv = TID >> 6;
    if (wv < 2) {
        const int* tot = (wv == 0) ? totEb : totTb;
        int* dst = (wv == 0) ? bksEs : bksTs;
        int carry = 0;
        for (int b2 = 0; b2 < NBKT; b2 += 64) {
            int idx = b2 + lane;
            int vv = (idx < NBKT) ? tot[idx] : 0;
            int incl = vv;
            #pragma unroll
            for (int off = 1; off < 64; off <<= 1) {
                int t = __shfl_up(incl, off, 64);
                if (lane >= off) incl += t;
            }
            if (idx < NBKT) dst[idx] = carry + incl - vv;
            carry += __shfl(incl, 63, 64);
        }
    }
    __syncthreads();
    const int b = blockIdx.x;
    for (int k = TID; k < NBKT; k += 256)
        cur[k] = bksEs[k] + (int)baseE[(size_t)k * NB2 + b];
    __syncthreads();
    const int e0 = b * CHE2, e1 = min(e0 + CHE2, NE);
    for (int i = e0 + TID; i < e1; i += 256) {
        int n0 = nl0[i];
        int pos = atomicAdd(&cur[n0 >> 6], 1);
        uint tq = (uint)fmaf(dist[i], 209715.2f, 0.5f);   // d * (4096/5) * 256
        eT[pos] = make_int2((int)(tq | ((uint)(n0 & 63) << 26)), nl1[i]);
    }
    __syncthreads();
    for (int k = TID; k < NBKT; k += 256)
        cur[k] = bksTs[k] + (int)baseT[(size_t)k * NB2 + b];
    __syncthreads();
    const int t0 = b * CHT2, tEnd = min(t0 + CHT2, NT);
    for (int i = t0 + TID; i < tEnd; i += 256) {
        int t1 = tidx[3 * i + 1];
        int pos = atomicAdd(&cur[t1 >> 6], 1);
        uint ab = ((uint)__half_as_ushort(__float2half_rn(rik[i])) << 16)
                | (uint)__half_as_ushort(__float2half_rn(rij[i]));
        uint cc = (uint)__half_as_ushort(__float2half_rn(__cosf(angles[i])))
                | ((uint)(t1 & 63) << 16);
        tT[pos] = make_int2((int)ab, (int)cc);
    }
}

// Phase-2: per bucket, exact node sort within the bucket window; bucket start inline.
__global__ __launch_bounds__(256) void k_nsort(const int2* __restrict__ eTs,
                                               const int2* __restrict__ tTs,
                                               const int* __restrict__ totEb,
                                               const int* __restrict__ totTb,
                                               int2* __restrict__ eS,
                                               int2* __restrict__ tS,
                                               int* __restrict__ startE,
                                               int* __restrict__ totE,
                                               int* __restrict__ startT,
                                               int* __restrict__ totT) {
    __shared__ int hist[64];
    __shared__ int cur[64];
    __shared__ int bksS[NBKT];
    const bool isE = blockIdx.x < NBKT;
    const int bkt = isE ? blockIdx.x : blockIdx.x - NBKT;
    const int2* src = isE ? eTs : tTs;
    int2* dst = isE ? eS : tS;
    const int* totB = isE ? totEb : totTb;
    int* stX = isE ? startE : startT;
    int* ttX = isE ? totE : totT;
    const int lane = TID & 63;
    const int wv = TID >> 6;
    if (wv == 0) {
        int carry = 0;
        for (int b2 = 0; b2 < NBKT; b2 += 64) {
            int idx = b2 + lane;
            int vv = (idx < NBKT) ? totB[idx] : 0;
            int incl = vv;
            #pragma unroll
            for (int off = 1; off < 64; off <<= 1) {
                int t = __shfl_up(incl, off, 64);
                if (lane >= off) incl += t;
            }
            if (idx < NBKT) bksS[idx] = carry + incl - vv;
            carry += __shfl(incl, 63, 64);
        }
    }
    if (TID < 64) hist[TID] = 0;
    __syncthreads();
    const int s0 = bksS[bkt];
    const int cnt = totB[bkt];
    for (int i = TID; i < cnt; i += 256) {
        int2 p = src[s0 + i];
        int nlo = isE ? (int)(((uint)p.x >> 26) & 63u) : (int)(((uint)p.y >> 16) & 63u);
        atomicAdd(&hist[nlo], 1);
    }
    __syncthreads();
    if (TID < 64) {                    // exactly wave 0
        int v = hist[TID];
        int incl = v;
        #pragma unroll
        for (int off = 1; off < 64; off <<= 1) {
            int t = __shfl_up(incl, off, 64);
            if (TID >= off) incl += t;
        }
        int excl = incl - v;
        cur[TID] = s0 + excl;
        int node = bkt * 64 + TID;
        if (node < NN) { stX[node] = s0 + excl; ttX[node] = v; }
    }
    __syncthreads();
    for (int i = TID; i < cnt; i += 256) {
        int2 p = src[s0 + i];
        int nlo = isE ? (int)(((uint)p.x >> 26) & 63u) : (int)(((uint)p.y >> 16) & 63u);
        int pos = atomicAdd(&cur[nlo], 1);
        dst[pos] = p;
    }
}

// Fused consumer: blocks [0,G_CONS_E) = edge path (lutP value+delta pairs, 2 gathers/edge);
// [G_CONS_E,+G_CONS_T) = triplet path.
__global__ __launch_bounds__(256) void k_consume(const int2* __restrict__ eS,
                                                 const int* __restrict__ startE,
                                                 const int* __restrict__ totE,
                                                 const ushort* __restrict__ hB,
                                                 const ushort* __restrict__ lutP,
                                                 float* __restrict__ agg,
                                                 const int2* __restrict__ tS,
                                                 const int* __restrict__ startT,
                                                 const int* __restrict__ totT,
                                                 const float* __restrict__ W3b1,
                                                 const float2* __restrict__ spLut,
                                                 float* __restrict__ uacc) {
    __shared__ __align__(16) char smem[10752];
    const int lane = TID & 63;
    const int wv = TID >> 6;
    if (blockIdx.x < G_CONS_E) {
        // ---------------- edge path ----------------
        int4 (*stage)[2][64] = (int4(*)[2][64])smem;   // 8 KB
        const int c8b = lane << 3;   // lutP: 8 B per lane
        const int c2b = lane << 2;   // hB:   4 B per lane
        for (int r = blockIdx.x * 4 + wv; r < NN; r += G_CONS_E * 4) {
            const int s0 = startE[r];
            const int cnt = totE[r];
            float a0 = 0.f, a1 = 0.f;
            int2 pf;
            if (lane < min(64, cnt)) pf = eS[s0 + lane];
            const int nch = (cnt + 63) >> 6;
            for (int c = 0; c < nch; ++c) {
                const int base = c << 6;
                const int n = min(64, cnt - base);
                const int slot = c & 1;
                if (lane < n) {
                    uint tq = ((uint)pf.x) & 0x03FFFFFFu;
                    int idx = min((int)(tq >> 8), LUTN - 2);
                    float fr = (float)(tq & 255u) * (1.0f / 256.0f);
                    stage[wv][slot][lane] = make_int4(idx << 9, __float_as_int(fr),
                                                      pf.y * (C * 2), 0);
                }
                int nb = base + 64;
                if (nb < cnt && lane < cnt - nb) pf = eS[s0 + nb + lane];   // prefetch
                asm volatile("s_waitcnt lgkmcnt(0)" ::: "memory");
                #pragma unroll 8
                for (int i = 0; i < n; ++i) {
                    int4 q = stage[wv][slot][i];     // uniform address -> LDS broadcast
                    float fr = __int_as_float(q.y);
                    ushort4 P = *(const ushort4*)((const char*)lutP + q.x + c8b);
                    ushort2 H2 = *(const ushort2*)((const char*)hB + q.z + c2b);
                    float ox = fmaf(fr, bf2f(P.y), bf2f(P.x));
                    float oy = fmaf(fr, bf2f(P.w), bf2f(P.z));
                    a0 = fmaf(ox, bf2f(H2.x), a0);
                    a1 = fmaf(oy, bf2f(H2.y), a1);
                }
            }
            asm volatile("s_waitcnt lgkmcnt(0)" ::: "memory");
            float2 o = {a0, a1};
            *(float2*)&agg[(size_t)r * C + (lane << 1)] = o;
        }
        return;
    }
    // ---------------- triplet path ----------------
    {
        uint* spl = (uint*)smem;                              // 2 KB
        float4 (*stage)[2][64] = (float4(*)[2][64])(smem + 2048);  // 8 KB
        for (int i = TID; i < 512; i += 256) {
            float2 vs = spLut[i];
            spl[i] = ((uint)f2bf(vs.y) << 16) | (uint)f2bf(vs.x);
        }
        __syncthreads();
        const float w1a = W3b1[lane];
        const float w1b = W3b1[64 + lane];
        const float w1c = W3b1[128 + lane];
        const int bid = blockIdx.x - G_CONS_E;
        for (int r = bid * 4 + wv; r < NN; r += G_CONS_T * 4) {
            const int s0 = startT[r];
            const int cnt = totT[r];
            float usA = 0.f, usB = 0.f;
            uint2 pf;
            if (lane < min(64, cnt)) pf = ((const uint2*)tS)[s0 + lane];
            const int nch = (cnt + 63) >> 6;
            for (int c = 0; c < nch; ++c) {
                const int base = c << 6;
                const int n = min(64, cnt - base);
                const int slot = c & 1;
                if (lane < n) {
                    float4 f;
                    f.x = h2f(pf.x);
                    f.y = h2f(pf.x >> 16);
                    f.z = h2f(pf.y);
                    f.w = 0.f;
                    stage[wv][slot][lane] = f;
                }
                int nb = base + 64;
                if (nb < cnt && lane < cnt - nb) pf = ((const uint2*)tS)[s0 + nb + lane];
                asm volatile("s_waitcnt lgkmcnt(0)" ::: "memory");
                int i = 0;
                #pragma unroll 4
                for (; i + 1 < n; i += 2) {
                    float4 pa = stage[wv][slot][i];
                    float4 pb = stage[wv][slot][i + 1];
                    float xa = fmaf(pa.x, w1a, fmaf(pa.y, w1b, pa.z * w1c));
                    float xb = fmaf(pb.x, w1a, fmaf(pb.y, w1b, pb.z * w1c));
                    float ta = fabsf(xa) * 32.0f;
                    float tb = fabsf(xb) * 32.0f;
                    int ia = min((int)ta, 511);
                    int ib = min((int)tb, 511);
                    float fa = ta - (float)ia;
                    float fb = tb - (float)ib;
                    uint va = spl[ia];
                    uint vb = spl[ib];
                    usA += fmaxf(xa, 0.f) + fmaf(fa, bf2f((ushort)(va >> 16)), bf2f((ushort)va));
                    usB += fmaxf(xb, 0.f) + fmaf(fb, bf2f((ushort)(vb >> 16)), bf2f((ushort)vb));
                }
                if (i < n) {
                    float4 pa = stage[wv][slot][i];
                    float xa = fmaf(pa.x, w1a, fmaf(pa.y, w1b, pa.z * w1c));
                    float ta = fabsf(xa) * 32.0f;
                    int ia = min((int)ta, 511);
                    float fa = ta - (float)ia;
                    uint va = spl[ia];
                    usA += fmaxf(xa, 0.f) + fmaf(fa, bf2f((ushort)(va >> 16)), bf2f((ushort)va));
                }
            }
            asm volatile("s_waitcnt lgkmcnt(0)" ::: "memory");
            uacc[(size_t)r * 64 + lane] = usA + usB - LN2 * (float)cnt;
        }
    }
}

// Dense epilogue GEMM: w3 = uacc @ W3b2; agg[nl0[r]] += hB[r] * w3 (consecutive atomics).
__global__ __launch_bounds__(256) void k_node_final(const float* __restrict__ uacc,
                                                    const float* __restrict__ W3b2,
                                                    const ushort* __restrict__ hB,
                                                    const int* __restrict__ nl0,
                                                    float* __restrict__ agg) {
    __shared__ uint w2p[64 * 64];   // 16 KB: packed {hi=col 64+l, lo=col l} bf16
    __shared__ float uL[16][68];    // 4.25 KB, padded rows
    for (int i = TID; i < 4096; i += 256) {
        int k = i >> 6, l = i & 63;
        w2p[i] = ((uint)f2bf(W3b2[k * C + 64 + l]) << 16) | (uint)f2bf(W3b2[k * C + l]);
    }
    const int base = blockIdx.x * 16;
    {
        int i = TID;
        int row = i >> 4, col = (i & 15) << 2;
        float4 v = ((const float4*)uacc)[(size_t)(base + row) * 16 + (i & 15)];
        *(float4*)&uL[row][col] = v;
    }
    __syncthreads();
    const int lane = TID & 63;
    const int wv = TID >> 6;
    #pragma unroll
    for (int j = 0; j < 4; ++j) {
        const int row = wv * 4 + j;
        float o0 = 0.f, o1 = 0.f;
        #pragma unroll 8
        for (int k = 0; k < 64; ++k) {
            float a = uL[row][k];            // wave-uniform broadcast read
            uint wp = w2p[k * 64 + lane];
            o0 = fmaf(a, __uint_as_float(wp << 16), o0);
            o1 = fmaf(a, __uint_as_float(wp & 0xFFFF0000u), o1);
        }
        const int r = base + row;
        const int n0 = nl0[r];
        float h0 = bf2f(hB[(size_t)r * C + lane]);
        float h1 = bf2f(hB[(size_t)r * C + 64 + lane]);
        unsafeAtomicAdd(&agg[(size_t)n0 * C + lane], o0 * h0);
        unsafeAtomicAdd(&agg[(size_t)n0 * C + 64 + lane], o1 * h1);
    }
}

// Final output GEMM (f32 out).
__global__ __launch_bounds__(256) void k_gemm16f(const float* __restrict__ A,
                                                 const float* __restrict__ W,
                                                 float* __restrict__ out, int nrows) {
    __shared__ ushort wB[C * C];
    __shared__ float aL[16][132];
    for (int i = TID; i < C * C / 4; i += 256) {
        float4 w4 = ((const float4*)W)[i];
        ushort4 u = {f2bf(w4.x), f2bf(w4.y), f2bf(w4.z), f2bf(w4.w)};
        ((ushort4*)wB)[i] = u;
    }
    const int base = blockIdx.x * 16;
    for (int i = TID; i < 512; i += 256) {
        int r = base + (i >> 5);
        float4 v = (r < nrows) ? ((const float4*)A)[(size_t)r * 32 + (i & 31)]
                               : (float4){0.f, 0.f, 0.f, 0.f};
        *(float4*)&aL[i >> 5][(i & 31) << 2] = v;
    }
    __syncthreads();
    const int rg = TID >> 4;
    const int c8 = (TID & 15) << 3;
    float acc[8] = {0.f, 0.f, 0.f, 0.f, 0.f, 0.f, 0.f, 0.f};
    #pragma unroll 8
    for (int k = 0; k < C; ++k) {
        float a = aL[rg][k];
        u16x8 wv = *(const u16x8*)&wB[k * C + c8];
        #pragma unroll
        for (int j = 0; j < 8; ++j) acc[j] = fmaf(a, bf2f(wv[j]), acc[j]);
    }
    int r = base + rg;
    if (r < nrows) {
        float4 o0 = {acc[0], acc[1], acc[2], acc[3]};
        float4 o1 = {acc[4], acc[5], acc[6], acc[7]};
        *(float4*)&out[(size_t)r * C + c8] = o0;
        *(float4*)&out[(size_t)r * C + c8 + 4] = o1;
    }
}

extern "C" void kernel_launch(void* const* d_in, const int* in_sizes, int n_in,
                              void* d_out, int out_size, void* d_ws, size_t ws_size,
                              hipStream_t stream) {
    const float* features = (const float*)d_in[0];
    const float* ndist    = (const float*)d_in[1];
    const int*   nlist    = (const int*)d_in[2];
    const int*   tidx     = (const int*)d_in[3];
    const float* angles   = (const float*)d_in[4];
    const float* rij      = (const float*)d_in[5];
    const float* rik      = (const float*)d_in[6];
    const float* W_pre    = (const float*)d_in[7];
    const float* W2b1     = (const float*)d_in[8];
    const float* W2b2     = (const float*)d_in[9];
    const float* W3b1     = (const float*)d_in[10];
    const float* W3b2     = (const float*)d_in[11];
    const float* W_post   = (const float*)d_in[12];
    float* out = (float*)d_out;

    char* w = (char*)d_ws;
    // agg (10.24 MB) region: first 5.12 MB aliases eT (dead before agg is written)
    float* agg    = (float*)w;
    int2* eT      = (int2*)w;
    w += (size_t)NN * C * 4;                                   // 10.24 MB
    ushort* hB    = (ushort*)w;  w += (size_t)NN * C * 2;      // 5.12 MB
    ushort* lutB  = (ushort*)w;  w += (size_t)LUTN * C * 2;    // 1.05 MB
    ushort* lutP  = (ushort*)w;  w += (size_t)LUTN * C * 4;    // 2.10 MB (value+delta pairs)
    int2* eS      = (int2*)w;    w += (size_t)NE * 8;          // 5.12 MB
    int2* tS      = (int2*)w;    w += (size_t)NT * 8;          // 8 MB
    // tT (8 MB) dead after k_nsort; uacc (5.12 MB) aliases it.
    int2* tT      = (int2*)w;
    float* uacc   = (float*)w;
    w += (size_t)NT * 8;                                       // 8 MB
    uchar* cntE   = (uchar*)w;   w += (size_t)NBKT * NB2;      // 160 KB
    uchar* cntT   = (uchar*)w;   w += (size_t)NBKT * NB2;
    ushort* baseE = (ushort*)w;  w += (size_t)NBKT * NB2 * 2;  // 320 KB
    ushort* baseT = (ushort*)w;  w += (size_t)NBKT * NB2 * 2;
    int* totEb    = (int*)w;     w += 1280;
    int* totTb    = (int*)w;     w += 1280;
    int* startE   = (int*)w;     w += (size_t)NN * 4;
    int* totE     = (int*)w;     w += (size_t)NN * 4;
    int* startT   = (int*)w;     w += (size_t)NN * 4;
    int* totT     = (int*)w;     w += (size_t)NN * 4;
    float2* spLut = (float2*)w;  w += 512 * 8;                 // 4 KB

    const int* nl0 = nlist;
    const int* nl1 = nlist + NE;

    hipLaunchKernelGGL(k_front, dim3(G_GEMM + G_LUT + NB2), dim3(256), 0, stream,
                       features, W_pre, hB, W2b1, W2b2, lutB, spLut,
                       nl0, tidx, cntE, cntT);
    hipLaunchKernelGGL(k_mid, dim3(G_SCAN + G_PACK), dim3(256), 0, stream,
                       cntE, cntT, baseE, baseT, totEb, totTb, lutB, lutP);
    hipLaunchKernelGGL(k_bplace, dim3(NB2), dim3(256), 0, stream,
                       nl0, nl1, ndist, tidx, angles, rij, rik,
                       baseE, baseT, totEb, totTb, eT, tT);
    hipLaunchKernelGGL(k_nsort, dim3(2 * NBKT), dim3(256), 0, stream,
                       eT, tT, totEb, totTb,
                       eS, tS, startE, totE, startT, totT);
    hipLaunchKernelGGL(k_consume, dim3(G_CONS_E + G_CONS_T), dim3(256), 0, stream,
                       eS, startE, totE, hB, lutP, agg,
                       tS, startT, totT, W3b1, spLut, uacc);
    hipLaunchKernelGGL(k_node_final, dim3(NN / 16), dim3(256), 0, stream,
                       uacc, W3b2, hB, nl0, agg);
    hipLaunchKernelGGL(k_gemm16f, dim3((NN + 15) / 16), dim3(256), 0, stream,
                       agg, W_post, out, NN);
}

// Round 18
// 175.014 us; speedup vs baseline: 1.0457x; 1.0457x over previous
//
#include <hip/hip_runtime.h>
#include <hip/hip_fp16.h>
#include <math.h>

#define TID threadIdx.x

typedef ushort u16x8 __attribute__((ext_vector_type(8)));
typedef unsigned char uchar;

static constexpr int NN = 20000;
static constexpr int NE = 640000;
static constexpr int NT = 1000000;
static constexpr int C = 128;
static constexpr int E = 64;
static constexpr int LUTN = 4104;     // 4097 live rows + zero padding
static constexpr int NBKT = 313;      // buckets of 64 nodes (313*64 = 20032)
static constexpr int NB2 = 512;       // sort blocks
static constexpr int CHE2 = 1250;     // NE / 512
static constexpr int CHT2 = 1954;     // ceil(NT / 512)
static constexpr int G_GEMM = (NN + 15) / 16;    // 1250
static constexpr int G_LUT = (LUTN + 7) / 8 + 1; // 514 (last = spLut)
static constexpr int G_SCAN = (2 * NBKT + 3) / 4; // 157
static constexpr int G_CONS_E = 1024;
static constexpr int G_CONS_T = 1024;
static constexpr float CUT = 5.0f;
static constexpr float LN2 = 0.69314718055994530942f;

__device__ __forceinline__ float ssp(float x) {
    return fmaxf(x, 0.0f) + __logf(1.0f + __expf(-fabsf(x))) - LN2;
}

__device__ __forceinline__ ushort f2bf(float x) {
    uint u = __float_as_uint(x);
    return (ushort)((u + 0x7FFFu + ((u >> 16) & 1u)) >> 16);
}

__device__ __forceinline__ float bf2f(ushort u) {
    return __uint_as_float((uint)u << 16);
}

__device__ __forceinline__ float h2f(uint bits) {
    return __half2float(__ushort_as_half((ushort)(bits & 0xFFFFu)));
}

// ---- Fused front-end: [0,G_GEMM) gemm16b | [G_GEMM,+513) lutB | +513 spLut | rest bcount ----
__global__ __launch_bounds__(256) void k_front(const float* __restrict__ features,
                                               const float* __restrict__ W_pre,
                                               ushort* __restrict__ hB,
                                               const float* __restrict__ W2b1,
                                               const float* __restrict__ W2b2,
                                               ushort* __restrict__ lutB,
                                               float2* __restrict__ spLut,
                                               const int* __restrict__ nl0,
                                               const int* __restrict__ tidx,
                                               uchar* __restrict__ cntE,
                                               uchar* __restrict__ cntT) {
    __shared__ __align__(16) char smem[53248];
    const int bid = blockIdx.x;
    if (bid < G_GEMM) {
        ushort* wB = (ushort*)smem;                       // 32 KB
        float (*aL)[132] = (float(*)[132])(smem + 32768); // 8.25 KB
        for (int i = TID; i < C * C / 4; i += 256) {
            float4 w4 = ((const float4*)W_pre)[i];
            ushort4 u = {f2bf(w4.x), f2bf(w4.y), f2bf(w4.z), f2bf(w4.w)};
            ((ushort4*)wB)[i] = u;
        }
        const int base = bid * 16;
        for (int i = TID; i < 512; i += 256) {
            int r = base + (i >> 5);
            float4 v = (r < NN) ? ((const float4*)features)[(size_t)r * 32 + (i & 31)]
                                : (float4){0.f, 0.f, 0.f, 0.f};
            *(float4*)&aL[i >> 5][(i & 31) << 2] = v;
        }
        __syncthreads();
        const int rg = TID >> 4;
        const int c8 = (TID & 15) << 3;
        float acc[8] = {0.f, 0.f, 0.f, 0.f, 0.f, 0.f, 0.f, 0.f};
        #pragma unroll 8
        for (int k = 0; k < C; ++k) {
            float a = aL[rg][k];
            u16x8 wv = *(const u16x8*)&wB[k * C + c8];
            #pragma unroll
            for (int j = 0; j < 8; ++j) acc[j] = fmaf(a, bf2f(wv[j]), acc[j]);
        }
        int r = base + rg;
        if (r < NN) {
            u16x8 u;
            #pragma unroll
            for (int j = 0; j < 8; ++j) u[j] = f2bf(acc[j]);
            *(u16x8*)&hB[(size_t)r * C + c8] = u;
        }
        return;
    }
    if (bid < G_GEMM + G_LUT) {
        const int lb = bid - G_GEMM;
        if (lb == G_LUT - 1) {
            for (int e = TID; e < 512; e += 256) {
                float t0 = (float)e * (1.0f / 32.0f);
                float t1 = (float)(e + 1) * (1.0f / 32.0f);
                float v0 = log1pf(__expf(-t0));
                float v1 = log1pf(__expf(-t1));
                spLut[e] = make_float2(v0, v1 - v0);
            }
            return;
        }
        float* w1 = (float*)smem;                         // 16 KB
        float* w2 = (float*)(smem + 16384);               // 32 KB
        float (*rbL)[E] = (float(*)[E])(smem + 49152);    // 2 KB
        float (*hid)[E] = (float(*)[E])(smem + 51200);    // 2 KB
        for (int i = TID; i < E * E; i += 256) w1[i] = W2b1[i];
        for (int i = TID; i < E * C; i += 256) w2[i] = W2b2[i];
        const int jj = TID & 63;
        const int esA = TID >> 6;
        const int eg = TID >> 5;
        const int c4 = (TID & 31) << 2;
        const float gamma = 81.92f;
        const float cstep = CUT / 63.0f;
        const float delta = CUT / 4096.0f;
        const int base = lb * 8;
        __syncthreads();
        #pragma unroll
        for (int s = 0; s < 2; ++s) {
            int es = esA + 4 * s;
            float d = (float)(base + es) * delta;
            float cv = (d < CUT) ? 0.5f * (1.0f + __cosf((float)M_PI * d / CUT)) : 0.0f;
            float dd = d - (float)jj * cstep;
            rbL[es][jj] = __expf(-gamma * dd * dd) * cv;
        }
        __syncthreads();
        #pragma unroll
        for (int s = 0; s < 2; ++s) {
            int es = esA + 4 * s;
            float a = 0.f;
            #pragma unroll 16
            for (int k = 0; k < E; ++k)
                a = fmaf(rbL[es][k], w1[k * E + jj], a);
            hid[es][jj] = ssp(a);
        }
        __syncthreads();
        float4 o = {0.f, 0.f, 0.f, 0.f};
        #pragma unroll
        for (int j = 0; j < E; ++j) {
            float t = hid[eg][j];
            const float4 w4 = *(const float4*)&w2[j * C + c4];
            o.x = fmaf(t, w4.x, o.x);
            o.y = fmaf(t, w4.y, o.y);
            o.z = fmaf(t, w4.z, o.z);
            o.w = fmaf(t, w4.w, o.w);
        }
        int row = base + eg;
        if (row < LUTN) {
            ushort4 u = {f2bf(o.x), f2bf(o.y), f2bf(o.z), f2bf(o.w)};
            *(ushort4*)&lutB[(size_t)row * C + c4] = u;
        }
        return;
    }
    // ---- bcount ----
    {
        int* h = (int*)smem;
        const int b = bid - G_GEMM - G_LUT;
        for (int i = TID; i < NBKT; i += 256) h[i] = 0;
        __syncthreads();
        const int e0 = b * CHE2, e1 = min(e0 + CHE2, NE);
        for (int i = e0 + TID; i < e1; i += 256) atomicAdd(&h[nl0[i] >> 6], 1);
        __syncthreads();
        for (int i = TID; i < NBKT; i += 256) { cntE[(size_t)i * NB2 + b] = (uchar)h[i]; h[i] = 0; }
        __syncthreads();
        const int t0 = b * CHT2, t1 = min(t0 + CHT2, NT);
        for (int i = t0 + TID; i < t1; i += 256) atomicAdd(&h[tidx[3 * i + 1] >> 6], 1);
        __syncthreads();
        for (int i = TID; i < NBKT; i += 256) cntT[(size_t)i * NB2 + b] = (uchar)h[i];
    }
}

// Mid: per-bucket scans across the 512 blocks -> bases (ushort) + bucket totals (int).
__global__ __launch_bounds__(256) void k_mid(const uchar* __restrict__ cE,
                                             const uchar* __restrict__ cT,
                                             ushort* __restrict__ baseE,
                                             ushort* __restrict__ baseT,
                                             int* __restrict__ totEb,
                                             int* __restrict__ totTb) {
    const int lane = TID & 63;
    const int wv = TID >> 6;
    int task = blockIdx.x * 4 + wv;
    if (task >= 2 * NBKT) return;
    const bool isE = task < NBKT;
    const int k = isE ? task : task - NBKT;
    const uchar* src = isE ? cE : cT;
    ushort* dst = isE ? baseE : baseT;
    int* dT = isE ? totEb : totTb;
    int v[8], pre[8], s = 0;
    #pragma unroll
    for (int j = 0; j < 8; ++j) {
        v[j] = src[(size_t)k * NB2 + lane * 8 + j];
        pre[j] = s;
        s += v[j];
    }
    int incl = s;
    #pragma unroll
    for (int off = 1; off < 64; off <<= 1) {
        int t = __shfl_up(incl, off, 64);
        if (lane >= off) incl += t;
    }
    int excl = incl - s;
    #pragma unroll
    for (int j = 0; j < 8; ++j)
        dst[(size_t)k * NB2 + lane * 8 + j] = (ushort)(excl + pre[j]);
    if (lane == 63) dT[k] = incl;
}

// Phase-1 placement into bucket regions; bucket starts computed inline (1 wave each).
__global__ __launch_bounds__(256) void k_bplace(const int* __restrict__ nl0,
                                                const int* __restrict__ nl1,
                                                const float* __restrict__ dist,
                                                const int* __restrict__ tidx,
                                                const float* __restrict__ angles,
                                                const float* __restrict__ rij,
                                                const float* __restrict__ rik,
                                                const ushort* __restrict__ baseE,
                                                const ushort* __restrict__ baseT,
                                                const int* __restrict__ totEb,
                                                const int* __restrict__ totTb,
                                                int2* __restrict__ eT,
                                                int2* __restrict__ tT) {
    __shared__ int cur[NBKT];
    __shared__ int bksEs[NBKT];
    __shared__ int bksTs[NBKT];
    const int lane = TID & 63;
    const int wv = TID >> 6;
    if (wv < 2) {
        const int* tot = (wv == 0) ? totEb : totTb;
        int* dst = (wv == 0) ? bksEs : bksTs;
        int carry = 0;
        for (int b2 = 0; b2 < NBKT; b2 += 64) {
            int idx = b2 + lane;
            int vv = (idx < NBKT) ? tot[idx] : 0;
            int incl = vv;
            #pragma unroll
            for (int off = 1; off < 64; off <<= 1) {
                int t = __shfl_up(incl, off, 64);
                if (lane >= off) incl += t;
            }
            if (idx < NBKT) dst[idx] = carry + incl - vv;
            carry += __shfl(incl, 63, 64);
        }
    }
    __syncthreads();
    const int b = blockIdx.x;
    for (int k = TID; k < NBKT; k += 256)
        cur[k] = bksEs[k] + (int)baseE[(size_t)k * NB2 + b];
    __syncthreads();
    const int e0 = b * CHE2, e1 = min(e0 + CHE2, NE);
    for (int i = e0 + TID; i < e1; i += 256) {
        int n0 = nl0[i];
        int pos = atomicAdd(&cur[n0 >> 6], 1);
        uint tq = (uint)fmaf(dist[i], 209715.2f, 0.5f);   // d * (4096/5) * 256
        eT[pos] = make_int2((int)(tq | ((uint)(n0 & 63) << 26)), nl1[i]);
    }
    __syncthreads();
    for (int k = TID; k < NBKT; k += 256)
        cur[k] = bksTs[k] + (int)baseT[(size_t)k * NB2 + b];
    __syncthreads();
    const int t0 = b * CHT2, tEnd = min(t0 + CHT2, NT);
    for (int i = t0 + TID; i < tEnd; i += 256) {
        int t1 = tidx[3 * i + 1];
        int pos = atomicAdd(&cur[t1 >> 6], 1);
        uint ab = ((uint)__half_as_ushort(__float2half_rn(rik[i])) << 16)
                | (uint)__half_as_ushort(__float2half_rn(rij[i]));
        uint cc = (uint)__half_as_ushort(__float2half_rn(__cosf(angles[i])))
                | ((uint)(t1 & 63) << 16);
        tT[pos] = make_int2((int)ab, (int)cc);
    }
}

// Phase-2: per bucket, exact node sort within the bucket window; bucket start inline.
__global__ __launch_bounds__(256) void k_nsort(const int2* __restrict__ eTs,
                                               const int2* __restrict__ tTs,
                                               const int* __restrict__ totEb,
                                               const int* __restrict__ totTb,
                                               int2* __restrict__ eS,
                                               int2* __restrict__ tS,
                                               int* __restrict__ startE,
                                               int* __restrict__ totE,
                                               int* __restrict__ startT,
                                               int* __restrict__ totT) {
    __shared__ int hist[64];
    __shared__ int cur[64];
    __shared__ int bksS[NBKT];
    const bool isE = blockIdx.x < NBKT;
    const int bkt = isE ? blockIdx.x : blockIdx.x - NBKT;
    const int2* src = isE ? eTs : tTs;
    int2* dst = isE ? eS : tS;
    const int* totB = isE ? totEb : totTb;
    int* stX = isE ? startE : startT;
    int* ttX = isE ? totE : totT;
    const int lane = TID & 63;
    const int wv = TID >> 6;
    if (wv == 0) {
        int carry = 0;
        for (int b2 = 0; b2 < NBKT; b2 += 64) {
            int idx = b2 + lane;
            int vv = (idx < NBKT) ? totB[idx] : 0;
            int incl = vv;
            #pragma unroll
            for (int off = 1; off < 64; off <<= 1) {
                int t = __shfl_up(incl, off, 64);
                if (lane >= off) incl += t;
            }
            if (idx < NBKT) bksS[idx] = carry + incl - vv;
            carry += __shfl(incl, 63, 64);
        }
    }
    if (TID < 64) hist[TID] = 0;
    __syncthreads();
    const int s0 = bksS[bkt];
    const int cnt = totB[bkt];
    for (int i = TID; i < cnt; i += 256) {
        int2 p = src[s0 + i];
        int nlo = isE ? (int)(((uint)p.x >> 26) & 63u) : (int)(((uint)p.y >> 16) & 63u);
        atomicAdd(&hist[nlo], 1);
    }
    __syncthreads();
    if (TID < 64) {                    // exactly wave 0
        int v = hist[TID];
        int incl = v;
        #pragma unroll
        for (int off = 1; off < 64; off <<= 1) {
            int t = __shfl_up(incl, off, 64);
            if (TID >= off) incl += t;
        }
        int excl = incl - v;
        cur[TID] = s0 + excl;
        int node = bkt * 64 + TID;
        if (node < NN) { stX[node] = s0 + excl; ttX[node] = v; }
    }
    __syncthreads();
    for (int i = TID; i < cnt; i += 256) {
        int2 p = src[s0 + i];
        int nlo = isE ? (int)(((uint)p.x >> 26) & 63u) : (int)(((uint)p.y >> 16) & 63u);
        int pos = atomicAdd(&cur[nlo], 1);
        dst[pos] = p;
    }
}

// Fused consumer: blocks [0,G_CONS_E) = edge path; [G_CONS_E,+G_CONS_T) = triplet path.
// (Round-16 edge path restored: two ushort2 lutB gathers -> L2 row reuse intact.)
__global__ __launch_bounds__(256) void k_consume(const int2* __restrict__ eS,
                                                 const int* __restrict__ startE,
                                                 const int* __restrict__ totE,
                                                 const ushort* __restrict__ hB,
                                                 const ushort* __restrict__ lutB,
                                                 float* __restrict__ agg,
                                                 const int2* __restrict__ tS,
                                                 const int* __restrict__ startT,
                                                 const int* __restrict__ totT,
                                                 const float* __restrict__ W3b1,
                                                 const float2* __restrict__ spLut,
                                                 float* __restrict__ uacc) {
    __shared__ __align__(16) char smem[10752];
    const int lane = TID & 63;
    const int wv = TID >> 6;
    if (blockIdx.x < G_CONS_E) {
        // ---------------- edge path (latency-bound) ----------------
        int4 (*stage)[2][64] = (int4(*)[2][64])smem;   // 8 KB
        const int c2b = lane << 2;
        for (int r = blockIdx.x * 4 + wv; r < NN; r += G_CONS_E * 4) {
            const int s0 = startE[r];
            const int cnt = totE[r];
            float a0 = 0.f, a1 = 0.f;
            int2 pf;
            if (lane < min(64, cnt)) pf = eS[s0 + lane];
            const int nch = (cnt + 63) >> 6;
            for (int c = 0; c < nch; ++c) {
                const int base = c << 6;
                const int n = min(64, cnt - base);
                const int slot = c & 1;
                if (lane < n) {
                    uint tq = ((uint)pf.x) & 0x03FFFFFFu;
                    int idx = min((int)(tq >> 8), LUTN - 2);
                    float fr = (float)(tq & 255u) * (1.0f / 256.0f);
                    stage[wv][slot][lane] = make_int4(idx * (C * 2), __float_as_int(fr),
                                                      pf.y * (C * 2), 0);
                }
                int nb = base + 64;
                if (nb < cnt && lane < cnt - nb) pf = eS[s0 + nb + lane];   // prefetch
                asm volatile("s_waitcnt lgkmcnt(0)" ::: "memory");
                #pragma unroll 8
                for (int i = 0; i < n; ++i) {
                    int4 q = stage[wv][slot][i];     // uniform address -> LDS broadcast
                    float fr = __int_as_float(q.y);
                    ushort2 A2 = *(const ushort2*)((const char*)lutB + q.x + c2b);
                    ushort2 B2 = *(const ushort2*)((const char*)lutB + q.x + 256 + c2b);
                    ushort2 H2 = *(const ushort2*)((const char*)hB + q.z + c2b);
                    float ax = bf2f(A2.x), ay = bf2f(A2.y);
                    float ox = fmaf(fr, bf2f(B2.x) - ax, ax);
                    float oy = fmaf(fr, bf2f(B2.y) - ay, ay);
                    a0 = fmaf(ox, bf2f(H2.x), a0);
                    a1 = fmaf(oy, bf2f(H2.y), a1);
                }
            }
            asm volatile("s_waitcnt lgkmcnt(0)" ::: "memory");
            float2 o = {a0, a1};
            *(float2*)&agg[(size_t)r * C + (lane << 1)] = o;
        }
        return;
    }
    // ---------------- triplet path (VALU-bound) ----------------
    {
        uint* spl = (uint*)smem;                              // 2 KB
        float4 (*stage)[2][64] = (float4(*)[2][64])(smem + 2048);  // 8 KB
        for (int i = TID; i < 512; i += 256) {
            float2 vs = spLut[i];
            spl[i] = ((uint)f2bf(vs.y) << 16) | (uint)f2bf(vs.x);
        }
        __syncthreads();
        const float w1a = W3b1[lane];
        const float w1b = W3b1[64 + lane];
        const float w1c = W3b1[128 + lane];
        const int bid = blockIdx.x - G_CONS_E;
        for (int r = bid * 4 + wv; r < NN; r += G_CONS_T * 4) {
            const int s0 = startT[r];
            const int cnt = totT[r];
            float usA = 0.f, usB = 0.f;
            uint2 pf;
            if (lane < min(64, cnt)) pf = ((const uint2*)tS)[s0 + lane];
            const int nch = (cnt + 63) >> 6;
            for (int c = 0; c < nch; ++c) {
                const int base = c << 6;
                const int n = min(64, cnt - base);
                const int slot = c & 1;
                if (lane < n) {
                    float4 f;
                    f.x = h2f(pf.x);
                    f.y = h2f(pf.x >> 16);
                    f.z = h2f(pf.y);
                    f.w = 0.f;
                    stage[wv][slot][lane] = f;
                }
                int nb = base + 64;
                if (nb < cnt && lane < cnt - nb) pf = ((const uint2*)tS)[s0 + nb + lane];
                asm volatile("s_waitcnt lgkmcnt(0)" ::: "memory");
                int i = 0;
                #pragma unroll 4
                for (; i + 1 < n; i += 2) {
                    float4 pa = stage[wv][slot][i];
                    float4 pb = stage[wv][slot][i + 1];
                    float xa = fmaf(pa.x, w1a, fmaf(pa.y, w1b, pa.z * w1c));
                    float xb = fmaf(pb.x, w1a, fmaf(pb.y, w1b, pb.z * w1c));
                    float ta = fabsf(xa) * 32.0f;
                    float tb = fabsf(xb) * 32.0f;
                    int ia = min((int)ta, 511);
                    int ib = min((int)tb, 511);
                    float fa = ta - (float)ia;
                    float fb = tb - (float)ib;
                    uint va = spl[ia];
                    uint vb = spl[ib];
                    usA += fmaxf(xa, 0.f) + fmaf(fa, bf2f((ushort)(va >> 16)), bf2f((ushort)va));
                    usB += fmaxf(xb, 0.f) + fmaf(fb, bf2f((ushort)(vb >> 16)), bf2f((ushort)vb));
                }
                if (i < n) {
                    float4 pa = stage[wv][slot][i];
                    float xa = fmaf(pa.x, w1a, fmaf(pa.y, w1b, pa.z * w1c));
                    float ta = fabsf(xa) * 32.0f;
                    int ia = min((int)ta, 511);
                    float fa = ta - (float)ia;
                    uint va = spl[ia];
                    usA += fmaxf(xa, 0.f) + fmaf(fa, bf2f((ushort)(va >> 16)), bf2f((ushort)va));
                }
            }
            asm volatile("s_waitcnt lgkmcnt(0)" ::: "memory");
            uacc[(size_t)r * 64 + lane] = usA + usB - LN2 * (float)cnt;
        }
    }
}

// Dense epilogue GEMM: w3 = uacc @ W3b2; agg[nl0[r]] += hB[r] * w3 (consecutive atomics).
__global__ __launch_bounds__(256) void k_node_final(const float* __restrict__ uacc,
                                                    const float* __restrict__ W3b2,
                                                    const ushort* __restrict__ hB,
                                                    const int* __restrict__ nl0,
                                                    float* __restrict__ agg) {
    __shared__ uint w2p[64 * 64];   // 16 KB: packed {hi=col 64+l, lo=col l} bf16
    __shared__ float uL[16][68];    // 4.25 KB, padded rows
    for (int i = TID; i < 4096; i += 256) {
        int k = i >> 6, l = i & 63;
        w2p[i] = ((uint)f2bf(W3b2[k * C + 64 + l]) << 16) | (uint)f2bf(W3b2[k * C + l]);
    }
    const int base = blockIdx.x * 16;
    {
        int i = TID;
        int row = i >> 4, col = (i & 15) << 2;
        float4 v = ((const float4*)uacc)[(size_t)(base + row) * 16 + (i & 15)];
        *(float4*)&uL[row][col] = v;
    }
    __syncthreads();
    const int lane = TID & 63;
    const int wv = TID >> 6;
    #pragma unroll
    for (int j = 0; j < 4; ++j) {
        const int row = wv * 4 + j;
        float o0 = 0.f, o1 = 0.f;
        #pragma unroll 8
        for (int k = 0; k < 64; ++k) {
            float a = uL[row][k];            // wave-uniform broadcast read
            uint wp = w2p[k * 64 + lane];
            o0 = fmaf(a, __uint_as_float(wp << 16), o0);
            o1 = fmaf(a, __uint_as_float(wp & 0xFFFF0000u), o1);
        }
        const int r = base + row;
        const int n0 = nl0[r];
        float h0 = bf2f(hB[(size_t)r * C + lane]);
        float h1 = bf2f(hB[(size_t)r * C + 64 + lane]);
        unsafeAtomicAdd(&agg[(size_t)n0 * C + lane], o0 * h0);
        unsafeAtomicAdd(&agg[(size_t)n0 * C + 64 + lane], o1 * h1);
    }
}

// Final output GEMM (f32 out).
__global__ __launch_bounds__(256) void k_gemm16f(const float* __restrict__ A,
                                                 const float* __restrict__ W,
                                                 float* __restrict__ out, int nrows) {
    __shared__ ushort wB[C * C];
    __shared__ float aL[16][132];
    for (int i = TID; i < C * C / 4; i += 256) {
        float4 w4 = ((const float4*)W)[i];
        ushort4 u = {f2bf(w4.x), f2bf(w4.y), f2bf(w4.z), f2bf(w4.w)};
        ((ushort4*)wB)[i] = u;
    }
    const int base = blockIdx.x * 16;
    for (int i = TID; i < 512; i += 256) {
        int r = base + (i >> 5);
        float4 v = (r < nrows) ? ((const float4*)A)[(size_t)r * 32 + (i & 31)]
                               : (float4){0.f, 0.f, 0.f, 0.f};
        *(float4*)&aL[i >> 5][(i & 31) << 2] = v;
    }
    __syncthreads();
    const int rg = TID >> 4;
    const int c8 = (TID & 15) << 3;
    float acc[8] = {0.f, 0.f, 0.f, 0.f, 0.f, 0.f, 0.f, 0.f};
    #pragma unroll 8
    for (int k = 0; k < C; ++k) {
        float a = aL[rg][k];
        u16x8 wv = *(const u16x8*)&wB[k * C + c8];
        #pragma unroll
        for (int j = 0; j < 8; ++j) acc[j] = fmaf(a, bf2f(wv[j]), acc[j]);
    }
    int r = base + rg;
    if (r < nrows) {
        float4 o0 = {acc[0], acc[1], acc[2], acc[3]};
        float4 o1 = {acc[4], acc[5], acc[6], acc[7]};
        *(float4*)&out[(size_t)r * C + c8] = o0;
        *(float4*)&out[(size_t)r * C + c8 + 4] = o1;
    }
}

extern "C" void kernel_launch(void* const* d_in, const int* in_sizes, int n_in,
                              void* d_out, int out_size, void* d_ws, size_t ws_size,
                              hipStream_t stream) {
    const float* features = (const float*)d_in[0];
    const float* ndist    = (const float*)d_in[1];
    const int*   nlist    = (const int*)d_in[2];
    const int*   tidx     = (const int*)d_in[3];
    const float* angles   = (const float*)d_in[4];
    const float* rij      = (const float*)d_in[5];
    const float* rik      = (const float*)d_in[6];
    const float* W_pre    = (const float*)d_in[7];
    const float* W2b1     = (const float*)d_in[8];
    const float* W2b2     = (const float*)d_in[9];
    const float* W3b1     = (const float*)d_in[10];
    const float* W3b2     = (const float*)d_in[11];
    const float* W_post   = (const float*)d_in[12];
    float* out = (float*)d_out;

    char* w = (char*)d_ws;
    // agg (10.24 MB) region: first 5.12 MB aliases eT (dead before agg is written)
    float* agg    = (float*)w;
    int2* eT      = (int2*)w;
    w += (size_t)NN * C * 4;                                   // 10.24 MB
    ushort* hB    = (ushort*)w;  w += (size_t)NN * C * 2;      // 5.12 MB
    ushort* lutB  = (ushort*)w;  w += (size_t)LUTN * C * 2;    // 1.05 MB
    int2* eS      = (int2*)w;    w += (size_t)NE * 8;          // 5.12 MB
    int2* tS      = (int2*)w;    w += (size_t)NT * 8;          // 8 MB
    // tT (8 MB) dead after k_nsort; uacc (5.12 MB) aliases it.
    int2* tT      = (int2*)w;
    float* uacc   = (float*)w;
    w += (size_t)NT * 8;                                       // 8 MB
    uchar* cntE   = (uchar*)w;   w += (size_t)NBKT * NB2;      // 160 KB
    uchar* cntT   = (uchar*)w;   w += (size_t)NBKT * NB2;
    ushort* baseE = (ushort*)w;  w += (size_t)NBKT * NB2 * 2;  // 320 KB
    ushort* baseT = (ushort*)w;  w += (size_t)NBKT * NB2 * 2;
    int* totEb    = (int*)w;     w += 1280;
    int* totTb    = (int*)w;     w += 1280;
    int* startE   = (int*)w;     w += (size_t)NN * 4;
    int* totE     = (int*)w;     w += (size_t)NN * 4;
    int* startT   = (int*)w;     w += (size_t)NN * 4;
    int* totT     = (int*)w;     w += (size_t)NN * 4;
    float2* spLut = (float2*)w;  w += 512 * 8;                 // 4 KB

    const int* nl0 = nlist;
    const int* nl1 = nlist + NE;

    hipLaunchKernelGGL(k_front, dim3(G_GEMM + G_LUT + NB2), dim3(256), 0, stream,
                       features, W_pre, hB, W2b1, W2b2, lutB, spLut,
                       nl0, tidx, cntE, cntT);
    hipLaunchKernelGGL(k_mid, dim3(G_SCAN), dim3(256), 0, stream,
                       cntE, cntT, baseE, baseT, totEb, totTb);
    hipLaunchKernelGGL(k_bplace, dim3(NB2), dim3(256), 0, stream,
                       nl0, nl1, ndist, tidx, angles, rij, rik,
                       baseE, baseT, totEb, totTb, eT, tT);
    hipLaunchKernelGGL(k_nsort, dim3(2 * NBKT), dim3(256), 0, stream,
                       eT, tT, totEb, totTb,
                       eS, tS, startE, totE, startT, totT);
    hipLaunchKernelGGL(k_consume, dim3(G_CONS_E + G_CONS_T), dim3(256), 0, stream,
                       eS, startE, totE, hB, lutB, agg,
                       tS, startT, totT, W3b1, spLut, uacc);
    hipLaunchKernelGGL(k_node_final, dim3(NN / 16), dim3(256), 0, stream,
                       uacc, W3b2, hB, nl0, agg);
    hipLaunchKernelGGL(k_gemm16f, dim3((NN + 15) / 16), dim3(256), 0, stream,
                       agg, W_post, out, NN);
}

// Round 19
// 173.612 us; speedup vs baseline: 1.0542x; 1.0081x over previous
//
#include <hip/hip_runtime.h>
#include <hip/hip_fp16.h>
#include <math.h>

#define TID threadIdx.x

typedef ushort u16x8 __attribute__((ext_vector_type(8)));
typedef unsigned char uchar;

static constexpr int NN = 20000;
static constexpr int NE = 640000;
static constexpr int NT = 1000000;
static constexpr int C = 128;
static constexpr int E = 64;
static constexpr int LUTN = 4104;     // 4097 live rows + zero padding
static constexpr int NBKT = 313;      // buckets of 64 nodes (313*64 = 20032)
static constexpr int NB2 = 512;       // sort blocks
static constexpr int CHE2 = 1250;     // NE / 512
static constexpr int CHT2 = 1954;     // ceil(NT / 512)
static constexpr int G_GEMM = (NN + 15) / 16;    // 1250
static constexpr int G_LUT = (LUTN + 7) / 8 + 1; // 514 (last = spLut)
static constexpr int G_SCAN = (2 * NBKT + 3) / 4; // 157
static constexpr int G_CONS = 2048;               // 8 blocks/CU exactly
static constexpr float CUT = 5.0f;
static constexpr float LN2 = 0.69314718055994530942f;

__device__ __forceinline__ float ssp(float x) {
    return fmaxf(x, 0.0f) + __logf(1.0f + __expf(-fabsf(x))) - LN2;
}

__device__ __forceinline__ ushort f2bf(float x) {
    uint u = __float_as_uint(x);
    return (ushort)((u + 0x7FFFu + ((u >> 16) & 1u)) >> 16);
}

__device__ __forceinline__ float bf2f(ushort u) {
    return __uint_as_float((uint)u << 16);
}

__device__ __forceinline__ float h2f(uint bits) {
    return __half2float(__ushort_as_half((ushort)(bits & 0xFFFFu)));
}

// ---- Fused front-end: [0,G_GEMM) gemm16b | [G_GEMM,+513) lutB | +513 spLut | rest bcount ----
__global__ __launch_bounds__(256) void k_front(const float* __restrict__ features,
                                               const float* __restrict__ W_pre,
                                               ushort* __restrict__ hB,
                                               const float* __restrict__ W2b1,
                                               const float* __restrict__ W2b2,
                                               ushort* __restrict__ lutB,
                                               float2* __restrict__ spLut,
                                               const int* __restrict__ nl0,
                                               const int* __restrict__ tidx,
                                               uchar* __restrict__ cntE,
                                               uchar* __restrict__ cntT) {
    __shared__ __align__(16) char smem[53248];
    const int bid = blockIdx.x;
    if (bid < G_GEMM) {
        ushort* wB = (ushort*)smem;                       // 32 KB
        float (*aL)[132] = (float(*)[132])(smem + 32768); // 8.25 KB
        for (int i = TID; i < C * C / 4; i += 256) {
            float4 w4 = ((const float4*)W_pre)[i];
            ushort4 u = {f2bf(w4.x), f2bf(w4.y), f2bf(w4.z), f2bf(w4.w)};
            ((ushort4*)wB)[i] = u;
        }
        const int base = bid * 16;
        for (int i = TID; i < 512; i += 256) {
            int r = base + (i >> 5);
            float4 v = (r < NN) ? ((const float4*)features)[(size_t)r * 32 + (i & 31)]
                                : (float4){0.f, 0.f, 0.f, 0.f};
            *(float4*)&aL[i >> 5][(i & 31) << 2] = v;
        }
        __syncthreads();
        const int rg = TID >> 4;
        const int c8 = (TID & 15) << 3;
        float acc[8] = {0.f, 0.f, 0.f, 0.f, 0.f, 0.f, 0.f, 0.f};
        #pragma unroll 8
        for (int k = 0; k < C; ++k) {
            float a = aL[rg][k];
            u16x8 wv = *(const u16x8*)&wB[k * C + c8];
            #pragma unroll
            for (int j = 0; j < 8; ++j) acc[j] = fmaf(a, bf2f(wv[j]), acc[j]);
        }
        int r = base + rg;
        if (r < NN) {
            u16x8 u;
            #pragma unroll
            for (int j = 0; j < 8; ++j) u[j] = f2bf(acc[j]);
            *(u16x8*)&hB[(size_t)r * C + c8] = u;
        }
        return;
    }
    if (bid < G_GEMM + G_LUT) {
        const int lb = bid - G_GEMM;
        if (lb == G_LUT - 1) {
            for (int e = TID; e < 512; e += 256) {
                float t0 = (float)e * (1.0f / 32.0f);
                float t1 = (float)(e + 1) * (1.0f / 32.0f);
                float v0 = log1pf(__expf(-t0));
                float v1 = log1pf(__expf(-t1));
                spLut[e] = make_float2(v0, v1 - v0);
            }
            return;
        }
        float* w1 = (float*)smem;                         // 16 KB
        float* w2 = (float*)(smem + 16384);               // 32 KB
        float (*rbL)[E] = (float(*)[E])(smem + 49152);    // 2 KB
        float (*hid)[E] = (float(*)[E])(smem + 51200);    // 2 KB
        for (int i = TID; i < E * E; i += 256) w1[i] = W2b1[i];
        for (int i = TID; i < E * C; i += 256) w2[i] = W2b2[i];
        const int jj = TID & 63;
        const int esA = TID >> 6;
        const int eg = TID >> 5;
        const int c4 = (TID & 31) << 2;
        const float gamma = 81.92f;
        const float cstep = CUT / 63.0f;
        const float delta = CUT / 4096.0f;
        const int base = lb * 8;
        __syncthreads();
        #pragma unroll
        for (int s = 0; s < 2; ++s) {
            int es = esA + 4 * s;
            float d = (float)(base + es) * delta;
            float cv = (d < CUT) ? 0.5f * (1.0f + __cosf((float)M_PI * d / CUT)) : 0.0f;
            float dd = d - (float)jj * cstep;
            rbL[es][jj] = __expf(-gamma * dd * dd) * cv;
        }
        __syncthreads();
        #pragma unroll
        for (int s = 0; s < 2; ++s) {
            int es = esA + 4 * s;
            float a = 0.f;
            #pragma unroll 16
            for (int k = 0; k < E; ++k)
                a = fmaf(rbL[es][k], w1[k * E + jj], a);
            hid[es][jj] = ssp(a);
        }
        __syncthreads();
        float4 o = {0.f, 0.f, 0.f, 0.f};
        #pragma unroll
        for (int j = 0; j < E; ++j) {
            float t = hid[eg][j];
            const float4 w4 = *(const float4*)&w2[j * C + c4];
            o.x = fmaf(t, w4.x, o.x);
            o.y = fmaf(t, w4.y, o.y);
            o.z = fmaf(t, w4.z, o.z);
            o.w = fmaf(t, w4.w, o.w);
        }
        int row = base + eg;
        if (row < LUTN) {
            ushort4 u = {f2bf(o.x), f2bf(o.y), f2bf(o.z), f2bf(o.w)};
            *(ushort4*)&lutB[(size_t)row * C + c4] = u;
        }
        return;
    }
    // ---- bcount ----
    {
        int* h = (int*)smem;
        const int b = bid - G_GEMM - G_LUT;
        for (int i = TID; i < NBKT; i += 256) h[i] = 0;
        __syncthreads();
        const int e0 = b * CHE2, e1 = min(e0 + CHE2, NE);
        for (int i = e0 + TID; i < e1; i += 256) atomicAdd(&h[nl0[i] >> 6], 1);
        __syncthreads();
        for (int i = TID; i < NBKT; i += 256) { cntE[(size_t)i * NB2 + b] = (uchar)h[i]; h[i] = 0; }
        __syncthreads();
        const int t0 = b * CHT2, t1 = min(t0 + CHT2, NT);
        for (int i = t0 + TID; i < t1; i += 256) atomicAdd(&h[tidx[3 * i + 1] >> 6], 1);
        __syncthreads();
        for (int i = TID; i < NBKT; i += 256) cntT[(size_t)i * NB2 + b] = (uchar)h[i];
    }
}

// Mid: per-bucket scans across the 512 blocks -> bases (ushort) + bucket totals (int).
__global__ __launch_bounds__(256) void k_mid(const uchar* __restrict__ cE,
                                             const uchar* __restrict__ cT,
                                             ushort* __restrict__ baseE,
                                             ushort* __restrict__ baseT,
                                             int* __restrict__ totEb,
                                             int* __restrict__ totTb) {
    const int lane = TID & 63;
    const int wv = TID >> 6;
    int task = blockIdx.x * 4 + wv;
    if (task >= 2 * NBKT) return;
    const bool isE = task < NBKT;
    const int k = isE ? task : task - NBKT;
    const uchar* src = isE ? cE : cT;
    ushort* dst = isE ? baseE : baseT;
    int* dT = isE ? totEb : totTb;
    int v[8], pre[8], s = 0;
    #pragma unroll
    for (int j = 0; j < 8; ++j) {
        v[j] = src[(size_t)k * NB2 + lane * 8 + j];
        pre[j] = s;
        s += v[j];
    }
    int incl = s;
    #pragma unroll
    for (int off = 1; off < 64; off <<= 1) {
        int t = __shfl_up(incl, off, 64);
        if (lane >= off) incl += t;
    }
    int excl = incl - s;
    #pragma unroll
    for (int j = 0; j < 8; ++j)
        dst[(size_t)k * NB2 + lane * 8 + j] = (ushort)(excl + pre[j]);
    if (lane == 63) dT[k] = incl;
}

// Phase-1 placement into bucket regions; bucket starts computed inline (1 wave each).
__global__ __launch_bounds__(256) void k_bplace(const int* __restrict__ nl0,
                                                const int* __restrict__ nl1,
                                                const float* __restrict__ dist,
                                                const int* __restrict__ tidx,
                                                const float* __restrict__ angles,
                                                const float* __restrict__ rij,
                                                const float* __restrict__ rik,
                                                const ushort* __restrict__ baseE,
                                                const ushort* __restrict__ baseT,
                                                const int* __restrict__ totEb,
                                                const int* __restrict__ totTb,
                                                int2* __restrict__ eT,
                                                int2* __restrict__ tT) {
    __shared__ int cur[NBKT];
    __shared__ int bksEs[NBKT];
    __shared__ int bksTs[NBKT];
    const int lane = TID & 63;
    const int wv = TID >> 6;
    if (wv < 2) {
        const int* tot = (wv == 0) ? totEb : totTb;
        int* dst = (wv == 0) ? bksEs : bksTs;
        int carry = 0;
        for (int b2 = 0; b2 < NBKT; b2 += 64) {
            int idx = b2 + lane;
            int vv = (idx < NBKT) ? tot[idx] : 0;
            int incl = vv;
            #pragma unroll
            for (int off = 1; off < 64; off <<= 1) {
                int t = __shfl_up(incl, off, 64);
                if (lane >= off) incl += t;
            }
            if (idx < NBKT) dst[idx] = carry + incl - vv;
            carry += __shfl(incl, 63, 64);
        }
    }
    __syncthreads();
    const int b = blockIdx.x;
    for (int k = TID; k < NBKT; k += 256)
        cur[k] = bksEs[k] + (int)baseE[(size_t)k * NB2 + b];
    __syncthreads();
    const int e0 = b * CHE2, e1 = min(e0 + CHE2, NE);
    for (int i = e0 + TID; i < e1; i += 256) {
        int n0 = nl0[i];
        int pos = atomicAdd(&cur[n0 >> 6], 1);
        uint tq = (uint)fmaf(dist[i], 209715.2f, 0.5f);   // d * (4096/5) * 256
        eT[pos] = make_int2((int)(tq | ((uint)(n0 & 63) << 26)), nl1[i]);
    }
    __syncthreads();
    for (int k = TID; k < NBKT; k += 256)
        cur[k] = bksTs[k] + (int)baseT[(size_t)k * NB2 + b];
    __syncthreads();
    const int t0 = b * CHT2, tEnd = min(t0 + CHT2, NT);
    for (int i = t0 + TID; i < tEnd; i += 256) {
        int t1 = tidx[3 * i + 1];
        int pos = atomicAdd(&cur[t1 >> 6], 1);
        uint ab = ((uint)__half_as_ushort(__float2half_rn(rik[i])) << 16)
                | (uint)__half_as_ushort(__float2half_rn(rij[i]));
        uint cc = (uint)__half_as_ushort(__float2half_rn(__cosf(angles[i])))
                | ((uint)(t1 & 63) << 16);
        tT[pos] = make_int2((int)ab, (int)cc);
    }
}

// Phase-2: per bucket, exact node sort within the bucket window; bucket start inline.
__global__ __launch_bounds__(256) void k_nsort(const int2* __restrict__ eTs,
                                               const int2* __restrict__ tTs,
                                               const int* __restrict__ totEb,
                                               const int* __restrict__ totTb,
                                               int2* __restrict__ eS,
                                               int2* __restrict__ tS,
                                               int* __restrict__ startE,
                                               int* __restrict__ totE,
                                               int* __restrict__ startT,
                                               int* __restrict__ totT) {
    __shared__ int hist[64];
    __shared__ int cur[64];
    __shared__ int bksS[NBKT];
    const bool isE = blockIdx.x < NBKT;
    const int bkt = isE ? blockIdx.x : blockIdx.x - NBKT;
    const int2* src = isE ? eTs : tTs;
    int2* dst = isE ? eS : tS;
    const int* totB = isE ? totEb : totTb;
    int* stX = isE ? startE : startT;
    int* ttX = isE ? totE : totT;
    const int lane = TID & 63;
    const int wv = TID >> 6;
    if (wv == 0) {
        int carry = 0;
        for (int b2 = 0; b2 < NBKT; b2 += 64) {
            int idx = b2 + lane;
            int vv = (idx < NBKT) ? totB[idx] : 0;
            int incl = vv;
            #pragma unroll
            for (int off = 1; off < 64; off <<= 1) {
                int t = __shfl_up(incl, off, 64);
                if (lane >= off) incl += t;
            }
            if (idx < NBKT) bksS[idx] = carry + incl - vv;
            carry += __shfl(incl, 63, 64);
        }
    }
    if (TID < 64) hist[TID] = 0;
    __syncthreads();
    const int s0 = bksS[bkt];
    const int cnt = totB[bkt];
    for (int i = TID; i < cnt; i += 256) {
        int2 p = src[s0 + i];
        int nlo = isE ? (int)(((uint)p.x >> 26) & 63u) : (int)(((uint)p.y >> 16) & 63u);
        atomicAdd(&hist[nlo], 1);
    }
    __syncthreads();
    if (TID < 64) {                    // exactly wave 0
        int v = hist[TID];
        int incl = v;
        #pragma unroll
        for (int off = 1; off < 64; off <<= 1) {
            int t = __shfl_up(incl, off, 64);
            if (TID >= off) incl += t;
        }
        int excl = incl - v;
        cur[TID] = s0 + excl;
        int node = bkt * 64 + TID;
        if (node < NN) { stX[node] = s0 + excl; ttX[node] = v; }
    }
    __syncthreads();
    for (int i = TID; i < cnt; i += 256) {
        int2 p = src[s0 + i];
        int nlo = isE ? (int)(((uint)p.x >> 26) & 63u) : (int)(((uint)p.y >> 16) & 63u);
        int pos = atomicAdd(&cur[nlo], 1);
        dst[pos] = p;
    }
}

// Phase-fused consumer: EVERY block runs edge phase then triplet phase over the
// same node stride -> per-block work is balanced, no half-residency tail.
// Waves at different phases co-schedule (VALU-bound trip ∥ latency-bound edges).
__global__ __launch_bounds__(256) void k_consume(const int2* __restrict__ eS,
                                                 const int* __restrict__ startE,
                                                 const int* __restrict__ totE,
                                                 const ushort* __restrict__ hB,
                                                 const ushort* __restrict__ lutB,
                                                 float* __restrict__ agg,
                                                 const int2* __restrict__ tS,
                                                 const int* __restrict__ startT,
                                                 const int* __restrict__ totT,
                                                 const float* __restrict__ W3b1,
                                                 const float2* __restrict__ spLut,
                                                 float* __restrict__ uacc) {
    __shared__ __align__(16) char smem[10496];   // spl [0,2K) + stage [2K,10.25K)
    uint* spl = (uint*)smem;
    const int lane = TID & 63;
    const int wv = TID >> 6;
    for (int i = TID; i < 512; i += 256) {
        float2 vs = spLut[i];
        spl[i] = ((uint)f2bf(vs.y) << 16) | (uint)f2bf(vs.x);
    }
    __syncthreads();
    // ---------------- edge phase (latency-bound) ----------------
    {
        int4 (*stage)[2][64] = (int4(*)[2][64])(smem + 2048);   // 8 KB, wave-private
        const int c2b = lane << 2;
        for (int r = blockIdx.x * 4 + wv; r < NN; r += G_CONS * 4) {
            const int s0 = startE[r];
            const int cnt = totE[r];
            float a0 = 0.f, a1 = 0.f;
            int2 pf;
            if (lane < min(64, cnt)) pf = eS[s0 + lane];
            const int nch = (cnt + 63) >> 6;
            for (int c = 0; c < nch; ++c) {
                const int base = c << 6;
                const int n = min(64, cnt - base);
                const int slot = c & 1;
                if (lane < n) {
                    uint tq = ((uint)pf.x) & 0x03FFFFFFu;
                    int idx = min((int)(tq >> 8), LUTN - 2);
                    float fr = (float)(tq & 255u) * (1.0f / 256.0f);
                    stage[wv][slot][lane] = make_int4(idx * (C * 2), __float_as_int(fr),
                                                      pf.y * (C * 2), 0);
                }
                int nb = base + 64;
                if (nb < cnt && lane < cnt - nb) pf = eS[s0 + nb + lane];   // prefetch
                asm volatile("s_waitcnt lgkmcnt(0)" ::: "memory");
                #pragma unroll 8
                for (int i = 0; i < n; ++i) {
                    int4 q = stage[wv][slot][i];     // uniform address -> LDS broadcast
                    float fr = __int_as_float(q.y);
                    ushort2 A2 = *(const ushort2*)((const char*)lutB + q.x + c2b);
                    ushort2 B2 = *(const ushort2*)((const char*)lutB + q.x + 256 + c2b);
                    ushort2 H2 = *(const ushort2*)((const char*)hB + q.z + c2b);
                    float ax = bf2f(A2.x), ay = bf2f(A2.y);
                    float ox = fmaf(fr, bf2f(B2.x) - ax, ax);
                    float oy = fmaf(fr, bf2f(B2.y) - ay, ay);
                    a0 = fmaf(ox, bf2f(H2.x), a0);
                    a1 = fmaf(oy, bf2f(H2.y), a1);
                }
            }
            asm volatile("s_waitcnt lgkmcnt(0)" ::: "memory");
            float2 o = {a0, a1};
            *(float2*)&agg[(size_t)r * C + (lane << 1)] = o;
        }
    }
    // ---------------- triplet phase (VALU-bound) ----------------
    {
        float4 (*stage)[2][64] = (float4(*)[2][64])(smem + 2048);  // reuses wave slot
        const float w1a = W3b1[lane];
        const float w1b = W3b1[64 + lane];
        const float w1c = W3b1[128 + lane];
        for (int r = blockIdx.x * 4 + wv; r < NN; r += G_CONS * 4) {
            const int s0 = startT[r];
            const int cnt = totT[r];
            float usA = 0.f, usB = 0.f;
            uint2 pf;
            if (lane < min(64, cnt)) pf = ((const uint2*)tS)[s0 + lane];
            const int nch = (cnt + 63) >> 6;
            for (int c = 0; c < nch; ++c) {
                const int base = c << 6;
                const int n = min(64, cnt - base);
                const int slot = c & 1;
                if (lane < n) {
                    float4 f;
                    f.x = h2f(pf.x);
                    f.y = h2f(pf.x >> 16);
                    f.z = h2f(pf.y);
                    f.w = 0.f;
                    stage[wv][slot][lane] = f;
                }
                int nb = base + 64;
                if (nb < cnt && lane < cnt - nb) pf = ((const uint2*)tS)[s0 + nb + lane];
                asm volatile("s_waitcnt lgkmcnt(0)" ::: "memory");
                int i = 0;
                #pragma unroll 4
                for (; i + 1 < n; i += 2) {
                    float4 pa = stage[wv][slot][i];
                    float4 pb = stage[wv][slot][i + 1];
                    float xa = fmaf(pa.x, w1a, fmaf(pa.y, w1b, pa.z * w1c));
                    float xb = fmaf(pb.x, w1a, fmaf(pb.y, w1b, pb.z * w1c));
                    float ta = fabsf(xa) * 32.0f;
                    float tb = fabsf(xb) * 32.0f;
                    int ia = min((int)ta, 511);
                    int ib = min((int)tb, 511);
                    float fa = ta - (float)ia;
                    float fb = tb - (float)ib;
                    uint va = spl[ia];
                    uint vb = spl[ib];
                    usA += fmaxf(xa, 0.f) + fmaf(fa, bf2f((ushort)(va >> 16)), bf2f((ushort)va));
                    usB += fmaxf(xb, 0.f) + fmaf(fb, bf2f((ushort)(vb >> 16)), bf2f((ushort)vb));
                }
                if (i < n) {
                    float4 pa = stage[wv][slot][i];
                    float xa = fmaf(pa.x, w1a, fmaf(pa.y, w1b, pa.z * w1c));
                    float ta = fabsf(xa) * 32.0f;
                    int ia = min((int)ta, 511);
                    float fa = ta - (float)ia;
                    uint va = spl[ia];
                    usA += fmaxf(xa, 0.f) + fmaf(fa, bf2f((ushort)(va >> 16)), bf2f((ushort)va));
                }
            }
            asm volatile("s_waitcnt lgkmcnt(0)" ::: "memory");
            uacc[(size_t)r * 64 + lane] = usA + usB - LN2 * (float)cnt;
        }
    }
}

// Dense epilogue GEMM: w3 = uacc @ W3b2; agg[nl0[r]] += hB[r] * w3 (consecutive atomics).
__global__ __launch_bounds__(256) void k_node_final(const float* __restrict__ uacc,
                                                    const float* __restrict__ W3b2,
                                                    const ushort* __restrict__ hB,
                                                    const int* __restrict__ nl0,
                                                    float* __restrict__ agg) {
    __shared__ uint w2p[64 * 64];   // 16 KB: packed {hi=col 64+l, lo=col l} bf16
    __shared__ float uL[16][68];    // 4.25 KB, padded rows
    for (int i = TID; i < 4096; i += 256) {
        int k = i >> 6, l = i & 63;
        w2p[i] = ((uint)f2bf(W3b2[k * C + 64 + l]) << 16) | (uint)f2bf(W3b2[k * C + l]);
    }
    const int base = blockIdx.x * 16;
    {
        int i = TID;
        int row = i >> 4, col = (i & 15) << 2;
        float4 v = ((const float4*)uacc)[(size_t)(base + row) * 16 + (i & 15)];
        *(float4*)&uL[row][col] = v;
    }
    __syncthreads();
    const int lane = TID & 63;
    const int wv = TID >> 6;
    #pragma unroll
    for (int j = 0; j < 4; ++j) {
        const int row = wv * 4 + j;
        float o0 = 0.f, o1 = 0.f;
        #pragma unroll 8
        for (int k = 0; k < 64; ++k) {
            float a = uL[row][k];            // wave-uniform broadcast read
            uint wp = w2p[k * 64 + lane];
            o0 = fmaf(a, __uint_as_float(wp << 16), o0);
            o1 = fmaf(a, __uint_as_float(wp & 0xFFFF0000u), o1);
        }
        const int r = base + row;
        const int n0 = nl0[r];
        float h0 = bf2f(hB[(size_t)r * C + lane]);
        float h1 = bf2f(hB[(size_t)r * C + 64 + lane]);
        unsafeAtomicAdd(&agg[(size_t)n0 * C + lane], o0 * h0);
        unsafeAtomicAdd(&agg[(size_t)n0 * C + 64 + lane], o1 * h1);
    }
}

// Final output GEMM (f32 out).
__global__ __launch_bounds__(256) void k_gemm16f(const float* __restrict__ A,
                                                 const float* __restrict__ W,
                                                 float* __restrict__ out, int nrows) {
    __shared__ ushort wB[C * C];
    __shared__ float aL[16][132];
    for (int i = TID; i < C * C / 4; i += 256) {
        float4 w4 = ((const float4*)W)[i];
        ushort4 u = {f2bf(w4.x), f2bf(w4.y), f2bf(w4.z), f2bf(w4.w)};
        ((ushort4*)wB)[i] = u;
    }
    const int base = blockIdx.x * 16;
    for (int i = TID; i < 512; i += 256) {
        int r = base + (i >> 5);
        float4 v = (r < nrows) ? ((const float4*)A)[(size_t)r * 32 + (i & 31)]
                               : (float4){0.f, 0.f, 0.f, 0.f};
        *(float4*)&aL[i >> 5][(i & 31) << 2] = v;
    }
    __syncthreads();
    const int rg = TID >> 4;
    const int c8 = (TID & 15) << 3;
    float acc[8] = {0.f, 0.f, 0.f, 0.f, 0.f, 0.f, 0.f, 0.f};
    #pragma unroll 8
    for (int k = 0; k < C; ++k) {
        float a = aL[rg][k];
        u16x8 wv = *(const u16x8*)&wB[k * C + c8];
        #pragma unroll
        for (int j = 0; j < 8; ++j) acc[j] = fmaf(a, bf2f(wv[j]), acc[j]);
    }
    int r = base + rg;
    if (r < nrows) {
        float4 o0 = {acc[0], acc[1], acc[2], acc[3]};
        float4 o1 = {acc[4], acc[5], acc[6], acc[7]};
        *(float4*)&out[(size_t)r * C + c8] = o0;
        *(float4*)&out[(size_t)r * C + c8 + 4] = o1;
    }
}

extern "C" void kernel_launch(void* const* d_in, const int* in_sizes, int n_in,
                              void* d_out, int out_size, void* d_ws, size_t ws_size,
                              hipStream_t stream) {
    const float* features = (const float*)d_in[0];
    const float* ndist    = (const float*)d_in[1];
    const int*   nlist    = (const int*)d_in[2];
    const int*   tidx     = (const int*)d_in[3];
    const float* angles   = (const float*)d_in[4];
    const float* rij      = (const float*)d_in[5];
    const float* rik      = (const float*)d_in[6];
    const float* W_pre    = (const float*)d_in[7];
    const float* W2b1     = (const float*)d_in[8];
    const float* W2b2     = (const float*)d_in[9];
    const float* W3b1     = (const float*)d_in[10];
    const float* W3b2     = (const float*)d_in[11];
    const float* W_post   = (const float*)d_in[12];
    float* out = (float*)d_out;

    char* w = (char*)d_ws;
    // agg (10.24 MB) region: first 5.12 MB aliases eT (dead before agg is written)
    float* agg    = (float*)w;
    int2* eT      = (int2*)w;
    w += (size_t)NN * C * 4;                                   // 10.24 MB
    ushort* hB    = (ushort*)w;  w += (size_t)NN * C * 2;      // 5.12 MB
    ushort* lutB  = (ushort*)w;  w += (size_t)LUTN * C * 2;    // 1.05 MB
    int2* eS      = (int2*)w;    w += (size_t)NE * 8;          // 5.12 MB
    int2* tS      = (int2*)w;    w += (size_t)NT * 8;          // 8 MB
    // tT (8 MB) dead after k_nsort; uacc (5.12 MB) aliases it.
    int2* tT      = (int2*)w;
    float* uacc   = (float*)w;
    w += (size_t)NT * 8;                                       // 8 MB
    uchar* cntE   = (uchar*)w;   w += (size_t)NBKT * NB2;      // 160 KB
    uchar* cntT   = (uchar*)w;   w += (size_t)NBKT * NB2;
    ushort* baseE = (ushort*)w;  w += (size_t)NBKT * NB2 * 2;  // 320 KB
    ushort* baseT = (ushort*)w;  w += (size_t)NBKT * NB2 * 2;
    int* totEb    = (int*)w;     w += 1280;
    int* totTb    = (int*)w;     w += 1280;
    int* startE   = (int*)w;     w += (size_t)NN * 4;
    int* totE     = (int*)w;     w += (size_t)NN * 4;
    int* startT   = (int*)w;     w += (size_t)NN * 4;
    int* totT     = (int*)w;     w += (size_t)NN * 4;
    float2* spLut = (float2*)w;  w += 512 * 8;                 // 4 KB

    const int* nl0 = nlist;
    const int* nl1 = nlist + NE;

    hipLaunchKernelGGL(k_front, dim3(G_GEMM + G_LUT + NB2), dim3(256), 0, stream,
                       features, W_pre, hB, W2b1, W2b2, lutB, spLut,
                       nl0, tidx, cntE, cntT);
    hipLaunchKernelGGL(k_mid, dim3(G_SCAN), dim3(256), 0, stream,
                       cntE, cntT, baseE, baseT, totEb, totTb);
    hipLaunchKernelGGL(k_bplace, dim3(NB2), dim3(256), 0, stream,
                       nl0, nl1, ndist, tidx, angles, rij, rik,
                       baseE, baseT, totEb, totTb, eT, tT);
    hipLaunchKernelGGL(k_nsort, dim3(2 * NBKT), dim3(256), 0, stream,
                       eT, tT, totEb, totTb,
                       eS, tS, startE, totE, startT, totT);
    hipLaunchKernelGGL(k_consume, dim3(G_CONS), dim3(256), 0, stream,
                       eS, startE, totE, hB, lutB, agg,
                       tS, startT, totT, W3b1, spLut, uacc);
    hipLaunchKernelGGL(k_node_final, dim3(NN / 16), dim3(256), 0, stream,
                       uacc, W3b2, hB, nl0, agg);
    hipLaunchKernelGGL(k_gemm16f, dim3((NN + 15) / 16), dim3(256), 0, stream,
                       agg, W_post, out, NN);
}

// Round 20
// 168.917 us; speedup vs baseline: 1.0835x; 1.0278x over previous
//
#include <hip/hip_runtime.h>
#include <hip/hip_fp16.h>
#include <math.h>

#define TID threadIdx.x

typedef ushort u16x8 __attribute__((ext_vector_type(8)));
typedef unsigned char uchar;

static constexpr int NN = 20000;
static constexpr int NE = 640000;
static constexpr int NT = 1000000;
static constexpr int C = 128;
static constexpr int E = 64;
static constexpr int LUTN = 4104;     // 4097 live rows + zero padding
static constexpr int NBKT = 625;      // buckets of 32 nodes (625*32 = 20000 exactly)
static constexpr int NB2 = 512;       // sort blocks
static constexpr int CHE2 = 1250;     // NE / 512
static constexpr int CHT2 = 1954;     // ceil(NT / 512)
static constexpr int G_GEMM = (NN + 15) / 16;    // 1250
static constexpr int G_LUT = (LUTN + 7) / 8 + 1; // 514 (last = spLut)
static constexpr int G_SCAN = (2 * NBKT + 3) / 4; // 313
static constexpr int SCAP = 2048;     // sorted[] capacity (>=11 sigma above max bucket)
static constexpr float CUT = 5.0f;
static constexpr float LN2 = 0.69314718055994530942f;

__device__ __forceinline__ float ssp(float x) {
    return fmaxf(x, 0.0f) + __logf(1.0f + __expf(-fabsf(x))) - LN2;
}

__device__ __forceinline__ ushort f2bf(float x) {
    uint u = __float_as_uint(x);
    return (ushort)((u + 0x7FFFu + ((u >> 16) & 1u)) >> 16);
}

__device__ __forceinline__ float bf2f(ushort u) {
    return __uint_as_float((uint)u << 16);
}

__device__ __forceinline__ float h2f(uint bits) {
    return __half2float(__ushort_as_half((ushort)(bits & 0xFFFFu)));
}

// ---- Fused front-end: [0,G_GEMM) gemm16b | [G_GEMM,+513) lutB | +513 spLut | rest bcount ----
__global__ __launch_bounds__(256) void k_front(const float* __restrict__ features,
                                               const float* __restrict__ W_pre,
                                               ushort* __restrict__ hB,
                                               const float* __restrict__ W2b1,
                                               const float* __restrict__ W2b2,
                                               ushort* __restrict__ lutB,
                                               float2* __restrict__ spLut,
                                               const int* __restrict__ nl0,
                                               const int* __restrict__ tidx,
                                               uchar* __restrict__ cntE,
                                               uchar* __restrict__ cntT) {
    __shared__ __align__(16) char smem[53248];
    const int bid = blockIdx.x;
    if (bid < G_GEMM) {
        ushort* wB = (ushort*)smem;                       // 32 KB
        float (*aL)[132] = (float(*)[132])(smem + 32768); // 8.25 KB
        for (int i = TID; i < C * C / 4; i += 256) {
            float4 w4 = ((const float4*)W_pre)[i];
            ushort4 u = {f2bf(w4.x), f2bf(w4.y), f2bf(w4.z), f2bf(w4.w)};
            ((ushort4*)wB)[i] = u;
        }
        const int base = bid * 16;
        for (int i = TID; i < 512; i += 256) {
            int r = base + (i >> 5);
            float4 v = (r < NN) ? ((const float4*)features)[(size_t)r * 32 + (i & 31)]
                                : (float4){0.f, 0.f, 0.f, 0.f};
            *(float4*)&aL[i >> 5][(i & 31) << 2] = v;
        }
        __syncthreads();
        const int rg = TID >> 4;
        const int c8 = (TID & 15) << 3;
        float acc[8] = {0.f, 0.f, 0.f, 0.f, 0.f, 0.f, 0.f, 0.f};
        #pragma unroll 8
        for (int k = 0; k < C; ++k) {
            float a = aL[rg][k];
            u16x8 wv = *(const u16x8*)&wB[k * C + c8];
            #pragma unroll
            for (int j = 0; j < 8; ++j) acc[j] = fmaf(a, bf2f(wv[j]), acc[j]);
        }
        int r = base + rg;
        if (r < NN) {
            u16x8 u;
            #pragma unroll
            for (int j = 0; j < 8; ++j) u[j] = f2bf(acc[j]);
            *(u16x8*)&hB[(size_t)r * C + c8] = u;
        }
        return;
    }
    if (bid < G_GEMM + G_LUT) {
        const int lb = bid - G_GEMM;
        if (lb == G_LUT - 1) {
            for (int e = TID; e < 512; e += 256) {
                float t0 = (float)e * (1.0f / 32.0f);
                float t1 = (float)(e + 1) * (1.0f / 32.0f);
                float v0 = log1pf(__expf(-t0));
                float v1 = log1pf(__expf(-t1));
                spLut[e] = make_float2(v0, v1 - v0);
            }
            return;
        }
        float* w1 = (float*)smem;                         // 16 KB
        float* w2 = (float*)(smem + 16384);               // 32 KB
        float (*rbL)[E] = (float(*)[E])(smem + 49152);    // 2 KB
        float (*hid)[E] = (float(*)[E])(smem + 51200);    // 2 KB
        for (int i = TID; i < E * E; i += 256) w1[i] = W2b1[i];
        for (int i = TID; i < E * C; i += 256) w2[i] = W2b2[i];
        const int jj = TID & 63;
        const int esA = TID >> 6;
        const int eg = TID >> 5;
        const int c4 = (TID & 31) << 2;
        const float gamma = 81.92f;
        const float cstep = CUT / 63.0f;
        const float delta = CUT / 4096.0f;
        const int base = lb * 8;
        __syncthreads();
        #pragma unroll
        for (int s = 0; s < 2; ++s) {
            int es = esA + 4 * s;
            float d = (float)(base + es) * delta;
            float cv = (d < CUT) ? 0.5f * (1.0f + __cosf((float)M_PI * d / CUT)) : 0.0f;
            float dd = d - (float)jj * cstep;
            rbL[es][jj] = __expf(-gamma * dd * dd) * cv;
        }
        __syncthreads();
        #pragma unroll
        for (int s = 0; s < 2; ++s) {
            int es = esA + 4 * s;
            float a = 0.f;
            #pragma unroll 16
            for (int k = 0; k < E; ++k)
                a = fmaf(rbL[es][k], w1[k * E + jj], a);
            hid[es][jj] = ssp(a);
        }
        __syncthreads();
        float4 o = {0.f, 0.f, 0.f, 0.f};
        #pragma unroll
        for (int j = 0; j < E; ++j) {
            float t = hid[eg][j];
            const float4 w4 = *(const float4*)&w2[j * C + c4];
            o.x = fmaf(t, w4.x, o.x);
            o.y = fmaf(t, w4.y, o.y);
            o.z = fmaf(t, w4.z, o.z);
            o.w = fmaf(t, w4.w, o.w);
        }
        int row = base + eg;
        if (row < LUTN) {
            ushort4 u = {f2bf(o.x), f2bf(o.y), f2bf(o.z), f2bf(o.w)};
            *(ushort4*)&lutB[(size_t)row * C + c4] = u;
        }
        return;
    }
    // ---- bcount (bucket = node >> 5) ----
    {
        int* h = (int*)smem;     // 2.5 KB
        const int b = bid - G_GEMM - G_LUT;
        for (int i = TID; i < NBKT; i += 256) h[i] = 0;
        __syncthreads();
        const int e0 = b * CHE2, e1 = min(e0 + CHE2, NE);
        for (int i = e0 + TID; i < e1; i += 256) atomicAdd(&h[nl0[i] >> 5], 1);
        __syncthreads();
        for (int i = TID; i < NBKT; i += 256) { cntE[(size_t)i * NB2 + b] = (uchar)h[i]; h[i] = 0; }
        __syncthreads();
        const int t0 = b * CHT2, t1 = min(t0 + CHT2, NT);
        for (int i = t0 + TID; i < t1; i += 256) atomicAdd(&h[tidx[3 * i + 1] >> 5], 1);
        __syncthreads();
        for (int i = TID; i < NBKT; i += 256) cntT[(size_t)i * NB2 + b] = (uchar)h[i];
    }
}

// Mid: per-bucket scans across the 512 blocks -> bases (ushort) + bucket totals (int).
__global__ __launch_bounds__(256) void k_mid(const uchar* __restrict__ cE,
                                             const uchar* __restrict__ cT,
                                             ushort* __restrict__ baseE,
                                             ushort* __restrict__ baseT,
                                             int* __restrict__ totEb,
                                             int* __restrict__ totTb) {
    const int lane = TID & 63;
    const int wv = TID >> 6;
    int task = blockIdx.x * 4 + wv;
    if (task >= 2 * NBKT) return;
    const bool isE = task < NBKT;
    const int k = isE ? task : task - NBKT;
    const uchar* src = isE ? cE : cT;
    ushort* dst = isE ? baseE : baseT;
    int* dT = isE ? totEb : totTb;
    int v[8], pre[8], s = 0;
    #pragma unroll
    for (int j = 0; j < 8; ++j) {
        v[j] = src[(size_t)k * NB2 + lane * 8 + j];
        pre[j] = s;
        s += v[j];
    }
    int incl = s;
    #pragma unroll
    for (int off = 1; off < 64; off <<= 1) {
        int t = __shfl_up(incl, off, 64);
        if (lane >= off) incl += t;
    }
    int excl = incl - s;
    #pragma unroll
    for (int j = 0; j < 8; ++j)
        dst[(size_t)k * NB2 + lane * 8 + j] = (ushort)(excl + pre[j]);
    if (lane == 63) dT[k] = incl;
}

// Phase-1 placement into bucket regions; bucket starts computed inline (1 wave each).
__global__ __launch_bounds__(256) void k_bplace(const int* __restrict__ nl0,
                                                const int* __restrict__ nl1,
                                                const float* __restrict__ dist,
                                                const int* __restrict__ tidx,
                                                const float* __restrict__ angles,
                                                const float* __restrict__ rij,
                                                const float* __restrict__ rik,
                                                const ushort* __restrict__ baseE,
                                                const ushort* __restrict__ baseT,
                                                const int* __restrict__ totEb,
                                                const int* __restrict__ totTb,
                                                int2* __restrict__ eT,
                                                int2* __restrict__ tT) {
    __shared__ int cur[NBKT];
    __shared__ int bksEs[NBKT];
    __shared__ int bksTs[NBKT];
    const int lane = TID & 63;
    const int wv = TID >> 6;
    if (wv < 2) {
        const int* tot = (wv == 0) ? totEb : totTb;
        int* dst = (wv == 0) ? bksEs : bksTs;
        int carry = 0;
        for (int b2 = 0; b2 < NBKT; b2 += 64) {
            int idx = b2 + lane;
            int vv = (idx < NBKT) ? tot[idx] : 0;
            int incl = vv;
            #pragma unroll
            for (int off = 1; off < 64; off <<= 1) {
                int t = __shfl_up(incl, off, 64);
                if (lane >= off) incl += t;
            }
            if (idx < NBKT) dst[idx] = carry + incl - vv;
            carry += __shfl(incl, 63, 64);
        }
    }
    __syncthreads();
    const int b = blockIdx.x;
    for (int k = TID; k < NBKT; k += 256)
        cur[k] = bksEs[k] + (int)baseE[(size_t)k * NB2 + b];
    __syncthreads();
    const int e0 = b * CHE2, e1 = min(e0 + CHE2, NE);
    for (int i = e0 + TID; i < e1; i += 256) {
        int n0 = nl0[i];
        int pos = atomicAdd(&cur[n0 >> 5], 1);
        uint tq = (uint)fmaf(dist[i], 209715.2f, 0.5f);   // d * (4096/5) * 256
        eT[pos] = make_int2((int)(tq | ((uint)(n0 & 31) << 26)), nl1[i]);
    }
    __syncthreads();
    for (int k = TID; k < NBKT; k += 256)
        cur[k] = bksTs[k] + (int)baseT[(size_t)k * NB2 + b];
    __syncthreads();
    const int t0 = b * CHT2, tEnd = min(t0 + CHT2, NT);
    for (int i = t0 + TID; i < tEnd; i += 256) {
        int t1 = tidx[3 * i + 1];
        int pos = atomicAdd(&cur[t1 >> 5], 1);
        uint ab = ((uint)__half_as_ushort(__float2half_rn(rik[i])) << 16)
                | (uint)__half_as_ushort(__float2half_rn(rij[i]));
        uint cc = (uint)__half_as_ushort(__float2half_rn(__cosf(angles[i])))
                | ((uint)(t1 & 31) << 16);
        tT[pos] = make_int2((int)ab, (int)cc);
    }
}

// Merged sort+consume: per bucket (32 nodes), sort its window into LDS, then
// consume straight from LDS uniform reads. grid: [0,NBKT)=E, [NBKT,2*NBKT)=T.
__global__ __launch_bounds__(256) void k_sortcons(const int2* __restrict__ eT,
                                                  const int2* __restrict__ tT,
                                                  const int* __restrict__ totEb,
                                                  const int* __restrict__ totTb,
                                                  const ushort* __restrict__ hB,
                                                  const ushort* __restrict__ lutB,
                                                  const float* __restrict__ W3b1,
                                                  const float2* __restrict__ spLut,
                                                  float* __restrict__ agg,
                                                  float* __restrict__ uacc) {
    __shared__ int2 sorted[SCAP];   // 16 KB
    __shared__ int hist[32], st[32], cur[32];
    __shared__ int bksS[NBKT];      // 2.5 KB
    __shared__ uint spl[512];       // 2 KB
    const bool isE = blockIdx.x < NBKT;
    const int bkt = isE ? blockIdx.x : blockIdx.x - NBKT;
    const int2* src = isE ? eT : tT;
    const int* totB = isE ? totEb : totTb;
    const int lane = TID & 63;
    const int wv = TID >> 6;
    for (int i = TID; i < 512; i += 256) {
        float2 vs = spLut[i];
        spl[i] = ((uint)f2bf(vs.y) << 16) | (uint)f2bf(vs.x);
    }
    if (wv == 0) {
        int carry = 0;
        for (int b2 = 0; b2 < NBKT; b2 += 64) {
            int idx = b2 + lane;
            int vv = (idx < NBKT) ? totB[idx] : 0;
            int incl = vv;
            #pragma unroll
            for (int off = 1; off < 64; off <<= 1) {
                int t = __shfl_up(incl, off, 64);
                if (lane >= off) incl += t;
            }
            if (idx < NBKT) bksS[idx] = carry + incl - vv;
            carry += __shfl(incl, 63, 64);
        }
    }
    if (TID < 32) hist[TID] = 0;
    __syncthreads();
    const int s0 = bksS[bkt];
    const int cnt = min(totB[bkt], SCAP);
    // pass 1: histogram (window is L2-resident; re-read in pass 2)
    for (int i = TID; i < cnt; i += 256) {
        int2 p = src[s0 + i];
        int nlo = isE ? (int)(((uint)p.x >> 26) & 31u) : (int)(((uint)p.y >> 16) & 31u);
        atomicAdd(&hist[nlo], 1);
    }
    __syncthreads();
    if (TID < 32) {                 // 32-lane scan in wave 0
        int v = hist[TID];
        int incl = v;
        #pragma unroll
        for (int off = 1; off < 32; off <<= 1) {
            int t = __shfl_up(incl, off, 64);
            if (TID >= off) incl += t;
        }
        st[TID] = incl - v;
        cur[TID] = incl - v;
    }
    __syncthreads();
    // pass 2: scatter into LDS
    for (int i = TID; i < cnt; i += 256) {
        int2 p = src[s0 + i];
        int nlo = isE ? (int)(((uint)p.x >> 26) & 31u) : (int)(((uint)p.y >> 16) & 31u);
        int pos = atomicAdd(&cur[nlo], 1);
        sorted[pos] = p;
    }
    __syncthreads();
    // consume: wave wv handles nodes wv*8 .. wv*8+7
    if (isE) {
        const int c2b = lane << 2;
        for (int j = wv * 8; j < wv * 8 + 8; ++j) {
            const int s = st[j];
            const int c = hist[j];
            float a0 = 0.f, a1 = 0.f;
            #pragma unroll 4
            for (int i = 0; i < c; ++i) {
                int2 p = sorted[s + i];          // uniform LDS read -> broadcast
                uint tq = (uint)p.x & 0x03FFFFFFu;
                int idx = min((int)(tq >> 8), LUTN - 2);
                float fr = (float)(tq & 255u) * (1.0f / 256.0f);
                ushort2 A2 = *(const ushort2*)((const char*)lutB + idx * (C * 2) + c2b);
                ushort2 B2 = *(const ushort2*)((const char*)lutB + idx * (C * 2) + 256 + c2b);
                ushort2 H2 = *(const ushort2*)((const char*)hB + p.y * (C * 2) + c2b);
                float ax = bf2f(A2.x), ay = bf2f(A2.y);
                float ox = fmaf(fr, bf2f(B2.x) - ax, ax);
                float oy = fmaf(fr, bf2f(B2.y) - ay, ay);
                a0 = fmaf(ox, bf2f(H2.x), a0);
                a1 = fmaf(oy, bf2f(H2.y), a1);
            }
            const int r = (bkt << 5) + j;
            float2 o = {a0, a1};
            *(float2*)&agg[(size_t)r * C + (lane << 1)] = o;
        }
    } else {
        const float w1a = W3b1[lane];
        const float w1b = W3b1[64 + lane];
        const float w1c = W3b1[128 + lane];
        for (int j = wv * 8; j < wv * 8 + 8; ++j) {
            const int s = st[j];
            const int c = hist[j];
            float usA = 0.f, usB = 0.f;
            int i = 0;
            #pragma unroll 4
            for (; i + 1 < c; i += 2) {
                int2 pa = sorted[s + i];
                int2 pb = sorted[s + i + 1];
                float xa = fmaf(h2f((uint)pa.x), w1a,
                          fmaf(h2f((uint)pa.x >> 16), w1b, h2f((uint)pa.y) * w1c));
                float xb = fmaf(h2f((uint)pb.x), w1a,
                          fmaf(h2f((uint)pb.x >> 16), w1b, h2f((uint)pb.y) * w1c));
                float ta = fabsf(xa) * 32.0f;
                float tb = fabsf(xb) * 32.0f;
                int ia = min((int)ta, 511);
                int ib = min((int)tb, 511);
                float fa = ta - (float)ia;
                float fb = tb - (float)ib;
                uint va = spl[ia];
                uint vb = spl[ib];
                usA += fmaxf(xa, 0.f) + fmaf(fa, bf2f((ushort)(va >> 16)), bf2f((ushort)va));
                usB += fmaxf(xb, 0.f) + fmaf(fb, bf2f((ushort)(vb >> 16)), bf2f((ushort)vb));
            }
            if (i < c) {
                int2 pa = sorted[s + i];
                float xa = fmaf(h2f((uint)pa.x), w1a,
                          fmaf(h2f((uint)pa.x >> 16), w1b, h2f((uint)pa.y) * w1c));
                float ta = fabsf(xa) * 32.0f;
                int ia = min((int)ta, 511);
                float fa = ta - (float)ia;
                uint va = spl[ia];
                usA += fmaxf(xa, 0.f) + fmaf(fa, bf2f((ushort)(va >> 16)), bf2f((ushort)va));
            }
            const int r = (bkt << 5) + j;
            uacc[(size_t)r * 64 + lane] = usA + usB - LN2 * (float)c;
        }
    }
}

// Dense epilogue GEMM: w3 = uacc @ W3b2; agg[nl0[r]] += hB[r] * w3 (consecutive atomics).
__global__ __launch_bounds__(256) void k_node_final(const float* __restrict__ uacc,
                                                    const float* __restrict__ W3b2,
                                                    const ushort* __restrict__ hB,
                                                    const int* __restrict__ nl0,
                                                    float* __restrict__ agg) {
    __shared__ uint w2p[64 * 64];   // 16 KB: packed {hi=col 64+l, lo=col l} bf16
    __shared__ float uL[16][68];    // 4.25 KB, padded rows
    for (int i = TID; i < 4096; i += 256) {
        int k = i >> 6, l = i & 63;
        w2p[i] = ((uint)f2bf(W3b2[k * C + 64 + l]) << 16) | (uint)f2bf(W3b2[k * C + l]);
    }
    const int base = blockIdx.x * 16;
    {
        int i = TID;
        int row = i >> 4, col = (i & 15) << 2;
        float4 v = ((const float4*)uacc)[(size_t)(base + row) * 16 + (i & 15)];
        *(float4*)&uL[row][col] = v;
    }
    __syncthreads();
    const int lane = TID & 63;
    const int wv = TID >> 6;
    #pragma unroll
    for (int j = 0; j < 4; ++j) {
        const int row = wv * 4 + j;
        float o0 = 0.f, o1 = 0.f;
        #pragma unroll 8
        for (int k = 0; k < 64; ++k) {
            float a = uL[row][k];            // wave-uniform broadcast read
            uint wp = w2p[k * 64 + lane];
            o0 = fmaf(a, __uint_as_float(wp << 16), o0);
            o1 = fmaf(a, __uint_as_float(wp & 0xFFFF0000u), o1);
        }
        const int r = base + row;
        const int n0 = nl0[r];
        float h0 = bf2f(hB[(size_t)r * C + lane]);
        float h1 = bf2f(hB[(size_t)r * C + 64 + lane]);
        unsafeAtomicAdd(&agg[(size_t)n0 * C + lane], o0 * h0);
        unsafeAtomicAdd(&agg[(size_t)n0 * C + 64 + lane], o1 * h1);
    }
}

// Final output GEMM (f32 out).
__global__ __launch_bounds__(256) void k_gemm16f(const float* __restrict__ A,
                                                 const float* __restrict__ W,
                                                 float* __restrict__ out, int nrows) {
    __shared__ ushort wB[C * C];
    __shared__ float aL[16][132];
    for (int i = TID; i < C * C / 4; i += 256) {
        float4 w4 = ((const float4*)W)[i];
        ushort4 u = {f2bf(w4.x), f2bf(w4.y), f2bf(w4.z), f2bf(w4.w)};
        ((ushort4*)wB)[i] = u;
    }
    const int base = blockIdx.x * 16;
    for (int i = TID; i < 512; i += 256) {
        int r = base + (i >> 5);
        float4 v = (r < nrows) ? ((const float4*)A)[(size_t)r * 32 + (i & 31)]
                               : (float4){0.f, 0.f, 0.f, 0.f};
        *(float4*)&aL[i >> 5][(i & 31) << 2] = v;
    }
    __syncthreads();
    const int rg = TID >> 4;
    const int c8 = (TID & 15) << 3;
    float acc[8] = {0.f, 0.f, 0.f, 0.f, 0.f, 0.f, 0.f, 0.f};
    #pragma unroll 8
    for (int k = 0; k < C; ++k) {
        float a = aL[rg][k];
        u16x8 wv = *(const u16x8*)&wB[k * C + c8];
        #pragma unroll
        for (int j = 0; j < 8; ++j) acc[j] = fmaf(a, bf2f(wv[j]), acc[j]);
    }
    int r = base + rg;
    if (r < nrows) {
        float4 o0 = {acc[0], acc[1], acc[2], acc[3]};
        float4 o1 = {acc[4], acc[5], acc[6], acc[7]};
        *(float4*)&out[(size_t)r * C + c8] = o0;
        *(float4*)&out[(size_t)r * C + c8 + 4] = o1;
    }
}

extern "C" void kernel_launch(void* const* d_in, const int* in_sizes, int n_in,
                              void* d_out, int out_size, void* d_ws, size_t ws_size,
                              hipStream_t stream) {
    const float* features = (const float*)d_in[0];
    const float* ndist    = (const float*)d_in[1];
    const int*   nlist    = (const int*)d_in[2];
    const int*   tidx     = (const int*)d_in[3];
    const float* angles   = (const float*)d_in[4];
    const float* rij      = (const float*)d_in[5];
    const float* rik      = (const float*)d_in[6];
    const float* W_pre    = (const float*)d_in[7];
    const float* W2b1     = (const float*)d_in[8];
    const float* W2b2     = (const float*)d_in[9];
    const float* W3b1     = (const float*)d_in[10];
    const float* W3b2     = (const float*)d_in[11];
    const float* W_post   = (const float*)d_in[12];
    float* out = (float*)d_out;

    char* w = (char*)d_ws;
    float* agg    = (float*)w;   w += (size_t)NN * C * 4;      // 10.24 MB (no aliasing)
    ushort* hB    = (ushort*)w;  w += (size_t)NN * C * 2;      // 5.12 MB
    ushort* lutB  = (ushort*)w;  w += (size_t)LUTN * C * 2;    // 1.05 MB
    int2* eT      = (int2*)w;    w += (size_t)NE * 8;          // 5.12 MB
    int2* tT      = (int2*)w;    w += (size_t)NT * 8;          // 8 MB
    float* uacc   = (float*)w;   w += (size_t)NN * 64 * 4;     // 5.12 MB
    uchar* cntE   = (uchar*)w;   w += (size_t)NBKT * NB2;      // 320 KB
    uchar* cntT   = (uchar*)w;   w += (size_t)NBKT * NB2;
    ushort* baseE = (ushort*)w;  w += (size_t)NBKT * NB2 * 2;  // 640 KB
    ushort* baseT = (ushort*)w;  w += (size_t)NBKT * NB2 * 2;
    int* totEb    = (int*)w;     w += (size_t)NBKT * 4;
    int* totTb    = (int*)w;     w += (size_t)NBKT * 4;
    float2* spLut = (float2*)w;  w += 512 * 8;                 // 4 KB

    const int* nl0 = nlist;
    const int* nl1 = nlist + NE;

    hipLaunchKernelGGL(k_front, dim3(G_GEMM + G_LUT + NB2), dim3(256), 0, stream,
                       features, W_pre, hB, W2b1, W2b2, lutB, spLut,
                       nl0, tidx, cntE, cntT);
    hipLaunchKernelGGL(k_mid, dim3(G_SCAN), dim3(256), 0, stream,
                       cntE, cntT, baseE, baseT, totEb, totTb);
    hipLaunchKernelGGL(k_bplace, dim3(NB2), dim3(256), 0, stream,
                       nl0, nl1, ndist, tidx, angles, rij, rik,
                       baseE, baseT, totEb, totTb, eT, tT);
    hipLaunchKernelGGL(k_sortcons, dim3(2 * NBKT), dim3(256), 0, stream,
                       eT, tT, totEb, totTb, hB, lutB, W3b1, spLut, agg, uacc);
    hipLaunchKernelGGL(k_node_final, dim3(NN / 16), dim3(256), 0, stream,
                       uacc, W3b2, hB, nl0, agg);
    hipLaunchKernelGGL(k_gemm16f, dim3((NN + 15) / 16), dim3(256), 0, stream,
                       agg, W_post, out, NN);
}

// Round 21
// 168.820 us; speedup vs baseline: 1.0841x; 1.0006x over previous
//
#include <hip/hip_runtime.h>
#include <hip/hip_fp16.h>
#include <math.h>

#define TID threadIdx.x

typedef ushort u16x8 __attribute__((ext_vector_type(8)));
typedef unsigned char uchar;

static constexpr int NN = 20000;
static constexpr int NE = 640000;
static constexpr int NT = 1000000;
static constexpr int C = 128;
static constexpr int E = 64;
static constexpr int LUTN = 4104;     // 4097 live rows + zero padding
static constexpr int NBKT = 625;      // buckets of 32 nodes (625*32 = 20000 exactly)
static constexpr int NB2 = 512;       // sort blocks
static constexpr int CHE2 = 1250;     // NE / 512
static constexpr int CHT2 = 1954;     // ceil(NT / 512)
static constexpr int G_GEMM = (NN + 15) / 16;    // 1250
static constexpr int G_LUT = (LUTN + 7) / 8 + 1; // 514 (last = spLut)
static constexpr int G_SCAN = (2 * NBKT + 3) / 4; // 313
static constexpr int SCAP = 2048;     // sorted[] capacity (>=11 sigma above max bucket)
static constexpr float CUT = 5.0f;
static constexpr float LN2 = 0.69314718055994530942f;

__device__ __forceinline__ float ssp(float x) {
    return fmaxf(x, 0.0f) + __logf(1.0f + __expf(-fabsf(x))) - LN2;
}

__device__ __forceinline__ ushort f2bf(float x) {
    uint u = __float_as_uint(x);
    return (ushort)((u + 0x7FFFu + ((u >> 16) & 1u)) >> 16);
}

__device__ __forceinline__ float bf2f(ushort u) {
    return __uint_as_float((uint)u << 16);
}

__device__ __forceinline__ float h2f(uint bits) {
    return __half2float(__ushort_as_half((ushort)(bits & 0xFFFFu)));
}

// ---- Fused front-end: [0,G_GEMM) gemm16b | [G_GEMM,+513) lutB | +513 spLut | rest bcount ----
__global__ __launch_bounds__(256) void k_front(const float* __restrict__ features,
                                               const float* __restrict__ W_pre,
                                               ushort* __restrict__ hB,
                                               const float* __restrict__ W2b1,
                                               const float* __restrict__ W2b2,
                                               ushort* __restrict__ lutB,
                                               float2* __restrict__ spLut,
                                               const int* __restrict__ nl0,
                                               const int* __restrict__ tidx,
                                               uchar* __restrict__ cntE,
                                               uchar* __restrict__ cntT,
                                               int* __restrict__ t1c) {
    __shared__ __align__(16) char smem[53248];
    const int bid = blockIdx.x;
    if (bid < G_GEMM) {
        ushort* wB = (ushort*)smem;                       // 32 KB
        float (*aL)[132] = (float(*)[132])(smem + 32768); // 8.25 KB
        for (int i = TID; i < C * C / 4; i += 256) {
            float4 w4 = ((const float4*)W_pre)[i];
            ushort4 u = {f2bf(w4.x), f2bf(w4.y), f2bf(w4.z), f2bf(w4.w)};
            ((ushort4*)wB)[i] = u;
        }
        const int base = bid * 16;
        for (int i = TID; i < 512; i += 256) {
            int r = base + (i >> 5);
            float4 v = (r < NN) ? ((const float4*)features)[(size_t)r * 32 + (i & 31)]
                                : (float4){0.f, 0.f, 0.f, 0.f};
            *(float4*)&aL[i >> 5][(i & 31) << 2] = v;
        }
        __syncthreads();
        const int rg = TID >> 4;
        const int c8 = (TID & 15) << 3;
        float acc[8] = {0.f, 0.f, 0.f, 0.f, 0.f, 0.f, 0.f, 0.f};
        #pragma unroll 8
        for (int k = 0; k < C; ++k) {
            float a = aL[rg][k];
            u16x8 wv = *(const u16x8*)&wB[k * C + c8];
            #pragma unroll
            for (int j = 0; j < 8; ++j) acc[j] = fmaf(a, bf2f(wv[j]), acc[j]);
        }
        int r = base + rg;
        if (r < NN) {
            u16x8 u;
            #pragma unroll
            for (int j = 0; j < 8; ++j) u[j] = f2bf(acc[j]);
            *(u16x8*)&hB[(size_t)r * C + c8] = u;
        }
        return;
    }
    if (bid < G_GEMM + G_LUT) {
        const int lb = bid - G_GEMM;
        if (lb == G_LUT - 1) {
            for (int e = TID; e < 512; e += 256) {
                float t0 = (float)e * (1.0f / 32.0f);
                float t1 = (float)(e + 1) * (1.0f / 32.0f);
                float v0 = log1pf(__expf(-t0));
                float v1 = log1pf(__expf(-t1));
                spLut[e] = make_float2(v0, v1 - v0);
            }
            return;
        }
        float* w1 = (float*)smem;                         // 16 KB
        float* w2 = (float*)(smem + 16384);               // 32 KB
        float (*rbL)[E] = (float(*)[E])(smem + 49152);    // 2 KB
        float (*hid)[E] = (float(*)[E])(smem + 51200);    // 2 KB
        for (int i = TID; i < E * E; i += 256) w1[i] = W2b1[i];
        for (int i = TID; i < E * C; i += 256) w2[i] = W2b2[i];
        const int jj = TID & 63;
        const int esA = TID >> 6;
        const int eg = TID >> 5;
        const int c4 = (TID & 31) << 2;
        const float gamma = 81.92f;
        const float cstep = CUT / 63.0f;
        const float delta = CUT / 4096.0f;
        const int base = lb * 8;
        __syncthreads();
        #pragma unroll
        for (int s = 0; s < 2; ++s) {
            int es = esA + 4 * s;
            float d = (float)(base + es) * delta;
            float cv = (d < CUT) ? 0.5f * (1.0f + __cosf((float)M_PI * d / CUT)) : 0.0f;
            float dd = d - (float)jj * cstep;
            rbL[es][jj] = __expf(-gamma * dd * dd) * cv;
        }
        __syncthreads();
        #pragma unroll
        for (int s = 0; s < 2; ++s) {
            int es = esA + 4 * s;
            float a = 0.f;
            #pragma unroll 16
            for (int k = 0; k < E; ++k)
                a = fmaf(rbL[es][k], w1[k * E + jj], a);
            hid[es][jj] = ssp(a);
        }
        __syncthreads();
        float4 o = {0.f, 0.f, 0.f, 0.f};
        #pragma unroll
        for (int j = 0; j < E; ++j) {
            float t = hid[eg][j];
            const float4 w4 = *(const float4*)&w2[j * C + c4];
            o.x = fmaf(t, w4.x, o.x);
            o.y = fmaf(t, w4.y, o.y);
            o.z = fmaf(t, w4.z, o.z);
            o.w = fmaf(t, w4.w, o.w);
        }
        int row = base + eg;
        if (row < LUTN) {
            ushort4 u = {f2bf(o.x), f2bf(o.y), f2bf(o.z), f2bf(o.w)};
            *(ushort4*)&lutB[(size_t)row * C + c4] = u;
        }
        return;
    }
    // ---- bcount (bucket = node >> 5); also emits compact t1c ----
    {
        int* h = (int*)smem;     // 2.5 KB
        const int b = bid - G_GEMM - G_LUT;
        for (int i = TID; i < NBKT; i += 256) h[i] = 0;
        __syncthreads();
        const int e0 = b * CHE2, e1 = min(e0 + CHE2, NE);
        for (int i = e0 + TID; i < e1; i += 256) atomicAdd(&h[nl0[i] >> 5], 1);
        __syncthreads();
        for (int i = TID; i < NBKT; i += 256) { cntE[(size_t)i * NB2 + b] = (uchar)h[i]; h[i] = 0; }
        __syncthreads();
        const int t0 = b * CHT2, t1 = min(t0 + CHT2, NT);
        for (int i = t0 + TID; i < t1; i += 256) {
            int tv = tidx[3 * i + 1];
            t1c[i] = tv;
            atomicAdd(&h[tv >> 5], 1);
        }
        __syncthreads();
        for (int i = TID; i < NBKT; i += 256) cntT[(size_t)i * NB2 + b] = (uchar)h[i];
    }
}

// Mid: per-bucket scans across the 512 blocks -> bases (ushort) + bucket totals (int).
__global__ __launch_bounds__(256) void k_mid(const uchar* __restrict__ cE,
                                             const uchar* __restrict__ cT,
                                             ushort* __restrict__ baseE,
                                             ushort* __restrict__ baseT,
                                             int* __restrict__ totEb,
                                             int* __restrict__ totTb) {
    const int lane = TID & 63;
    const int wv = TID >> 6;
    int task = blockIdx.x * 4 + wv;
    if (task >= 2 * NBKT) return;
    const bool isE = task < NBKT;
    const int k = isE ? task : task - NBKT;
    const uchar* src = isE ? cE : cT;
    ushort* dst = isE ? baseE : baseT;
    int* dT = isE ? totEb : totTb;
    int v[8], pre[8], s = 0;
    #pragma unroll
    for (int j = 0; j < 8; ++j) {
        v[j] = src[(size_t)k * NB2 + lane * 8 + j];
        pre[j] = s;
        s += v[j];
    }
    int incl = s;
    #pragma unroll
    for (int off = 1; off < 64; off <<= 1) {
        int t = __shfl_up(incl, off, 64);
        if (lane >= off) incl += t;
    }
    int excl = incl - s;
    #pragma unroll
    for (int j = 0; j < 8; ++j)
        dst[(size_t)k * NB2 + lane * 8 + j] = (ushort)(excl + pre[j]);
    if (lane == 63) dT[k] = incl;
}

// Phase-1 placement into bucket regions; bucket starts computed inline (1 wave each).
__global__ __launch_bounds__(256) void k_bplace(const int* __restrict__ nl0,
                                                const int* __restrict__ nl1,
                                                const float* __restrict__ dist,
                                                const int* __restrict__ t1c,
                                                const float* __restrict__ angles,
                                                const float* __restrict__ rij,
                                                const float* __restrict__ rik,
                                                const ushort* __restrict__ baseE,
                                                const ushort* __restrict__ baseT,
                                                const int* __restrict__ totEb,
                                                const int* __restrict__ totTb,
                                                int2* __restrict__ eT,
                                                int2* __restrict__ tT) {
    __shared__ int cur[NBKT];
    __shared__ int bksEs[NBKT];
    __shared__ int bksTs[NBKT];
    const int lane = TID & 63;
    const int wv = TID >> 6;
    if (wv < 2) {
        const int* tot = (wv == 0) ? totEb : totTb;
        int* dst = (wv == 0) ? bksEs : bksTs;
        int carry = 0;
        for (int b2 = 0; b2 < NBKT; b2 += 64) {
            int idx = b2 + lane;
            int vv = (idx < NBKT) ? tot[idx] : 0;
            int incl = vv;
            #pragma unroll
            for (int off = 1; off < 64; off <<= 1) {
                int t = __shfl_up(incl, off, 64);
                if (lane >= off) incl += t;
            }
            if (idx < NBKT) dst[idx] = carry + incl - vv;
            carry += __shfl(incl, 63, 64);
        }
    }
    __syncthreads();
    const int b = blockIdx.x;
    for (int k = TID; k < NBKT; k += 256)
        cur[k] = bksEs[k] + (int)baseE[(size_t)k * NB2 + b];
    __syncthreads();
    const int e0 = b * CHE2, e1 = min(e0 + CHE2, NE);
    for (int i = e0 + TID; i < e1; i += 256) {
        int n0 = nl0[i];
        int pos = atomicAdd(&cur[n0 >> 5], 1);
        uint tq = (uint)fmaf(dist[i], 209715.2f, 0.5f);   // d * (4096/5) * 256
        eT[pos] = make_int2((int)(tq | ((uint)(n0 & 31) << 26)), nl1[i]);
    }
    __syncthreads();
    for (int k = TID; k < NBKT; k += 256)
        cur[k] = bksTs[k] + (int)baseT[(size_t)k * NB2 + b];
    __syncthreads();
    const int t0 = b * CHT2, tEnd = min(t0 + CHT2, NT);
    for (int i = t0 + TID; i < tEnd; i += 256) {
        int t1 = t1c[i];
        int pos = atomicAdd(&cur[t1 >> 5], 1);
        uint ab = ((uint)__half_as_ushort(__float2half_rn(rik[i])) << 16)
                | (uint)__half_as_ushort(__float2half_rn(rij[i]));
        uint cc = (uint)__half_as_ushort(__float2half_rn(__cosf(angles[i])))
                | ((uint)(t1 & 31) << 16);
        tT[pos] = make_int2((int)ab, (int)cc);
    }
}

// Merged sort+consume: per bucket (32 nodes), sort its window into LDS, then
// consume from LDS uniform reads; DYNAMIC node->wave assignment (LDS cursor).
__global__ __launch_bounds__(256) void k_sortcons(const int2* __restrict__ eT,
                                                  const int2* __restrict__ tT,
                                                  const int* __restrict__ totEb,
                                                  const int* __restrict__ totTb,
                                                  const ushort* __restrict__ hB,
                                                  const ushort* __restrict__ lutB,
                                                  const float* __restrict__ W3b1,
                                                  const float2* __restrict__ spLut,
                                                  float* __restrict__ agg,
                                                  float* __restrict__ uacc) {
    __shared__ int2 sorted[SCAP];   // 16 KB
    __shared__ int hist[32], st[32], cur[32];
    __shared__ int bksS[NBKT];      // 2.5 KB
    __shared__ uint spl[512];       // 2 KB
    __shared__ int nextN;
    const bool isE = blockIdx.x < NBKT;
    const int bkt = isE ? blockIdx.x : blockIdx.x - NBKT;
    const int2* src = isE ? eT : tT;
    const int* totB = isE ? totEb : totTb;
    const int lane = TID & 63;
    const int wv = TID >> 6;
    for (int i = TID; i < 512; i += 256) {
        float2 vs = spLut[i];
        spl[i] = ((uint)f2bf(vs.y) << 16) | (uint)f2bf(vs.x);
    }
    if (wv == 0) {
        int carry = 0;
        for (int b2 = 0; b2 < NBKT; b2 += 64) {
            int idx = b2 + lane;
            int vv = (idx < NBKT) ? totB[idx] : 0;
            int incl = vv;
            #pragma unroll
            for (int off = 1; off < 64; off <<= 1) {
                int t = __shfl_up(incl, off, 64);
                if (lane >= off) incl += t;
            }
            if (idx < NBKT) bksS[idx] = carry + incl - vv;
            carry += __shfl(incl, 63, 64);
        }
    }
    if (TID < 32) hist[TID] = 0;
    if (TID == 32) nextN = 0;
    __syncthreads();
    const int s0 = bksS[bkt];
    const int cnt = min(totB[bkt], SCAP);
    // pass 1: histogram (window is L2-resident; re-read in pass 2)
    for (int i = TID; i < cnt; i += 256) {
        int2 p = src[s0 + i];
        int nlo = isE ? (int)(((uint)p.x >> 26) & 31u) : (int)(((uint)p.y >> 16) & 31u);
        atomicAdd(&hist[nlo], 1);
    }
    __syncthreads();
    if (TID < 32) {                 // 32-lane scan in wave 0
        int v = hist[TID];
        int incl = v;
        #pragma unroll
        for (int off = 1; off < 32; off <<= 1) {
            int t = __shfl_up(incl, off, 64);
            if (TID >= off) incl += t;
        }
        st[TID] = incl - v;
        cur[TID] = incl - v;
    }
    __syncthreads();
    // pass 2: scatter into LDS
    for (int i = TID; i < cnt; i += 256) {
        int2 p = src[s0 + i];
        int nlo = isE ? (int)(((uint)p.x >> 26) & 31u) : (int)(((uint)p.y >> 16) & 31u);
        int pos = atomicAdd(&cur[nlo], 1);
        sorted[pos] = p;
    }
    __syncthreads();
    // consume: waves grab nodes dynamically
    if (isE) {
        const int c2b = lane << 2;
        for (;;) {
            int j;
            if (lane == 0) j = atomicAdd(&nextN, 1);
            j = __shfl(j, 0, 64);
            if (j >= 32) break;
            const int s = st[j];
            const int c = hist[j];
            float a0 = 0.f, a1 = 0.f;
            #pragma unroll 4
            for (int i = 0; i < c; ++i) {
                int2 p = sorted[s + i];          // uniform LDS read -> broadcast
                uint tq = (uint)p.x & 0x03FFFFFFu;
                int idx = min((int)(tq >> 8), LUTN - 2);
                float fr = (float)(tq & 255u) * (1.0f / 256.0f);
                ushort2 A2 = *(const ushort2*)((const char*)lutB + idx * (C * 2) + c2b);
                ushort2 B2 = *(const ushort2*)((const char*)lutB + idx * (C * 2) + 256 + c2b);
                ushort2 H2 = *(const ushort2*)((const char*)hB + p.y * (C * 2) + c2b);
                float ax = bf2f(A2.x), ay = bf2f(A2.y);
                float ox = fmaf(fr, bf2f(B2.x) - ax, ax);
                float oy = fmaf(fr, bf2f(B2.y) - ay, ay);
                a0 = fmaf(ox, bf2f(H2.x), a0);
                a1 = fmaf(oy, bf2f(H2.y), a1);
            }
            const int r = (bkt << 5) + j;
            float2 o = {a0, a1};
            *(float2*)&agg[(size_t)r * C + (lane << 1)] = o;
        }
    } else {
        const float w1a = W3b1[lane];
        const float w1b = W3b1[64 + lane];
        const float w1c = W3b1[128 + lane];
        for (;;) {
            int j;
            if (lane == 0) j = atomicAdd(&nextN, 1);
            j = __shfl(j, 0, 64);
            if (j >= 32) break;
            const int s = st[j];
            const int c = hist[j];
            float usA = 0.f, usB = 0.f;
            int i = 0;
            #pragma unroll 4
            for (; i + 1 < c; i += 2) {
                int2 pa = sorted[s + i];
                int2 pb = sorted[s + i + 1];
                float xa = fmaf(h2f((uint)pa.x), w1a,
                          fmaf(h2f((uint)pa.x >> 16), w1b, h2f((uint)pa.y) * w1c));
                float xb = fmaf(h2f((uint)pb.x), w1a,
                          fmaf(h2f((uint)pb.x >> 16), w1b, h2f((uint)pb.y) * w1c));
                float ta = fabsf(xa) * 32.0f;
                float tb = fabsf(xb) * 32.0f;
                int ia = min((int)ta, 511);
                int ib = min((int)tb, 511);
                float fa = ta - (float)ia;
                float fb = tb - (float)ib;
                uint va = spl[ia];
                uint vb = spl[ib];
                usA += fmaxf(xa, 0.f) + fmaf(fa, bf2f((ushort)(va >> 16)), bf2f((ushort)va));
                usB += fmaxf(xb, 0.f) + fmaf(fb, bf2f((ushort)(vb >> 16)), bf2f((ushort)vb));
            }
            if (i < c) {
                int2 pa = sorted[s + i];
                float xa = fmaf(h2f((uint)pa.x), w1a,
                          fmaf(h2f((uint)pa.x >> 16), w1b, h2f((uint)pa.y) * w1c));
                float ta = fabsf(xa) * 32.0f;
                int ia = min((int)ta, 511);
                float fa = ta - (float)ia;
                uint va = spl[ia];
                usA += fmaxf(xa, 0.f) + fmaf(fa, bf2f((ushort)(va >> 16)), bf2f((ushort)va));
            }
            const int r = (bkt << 5) + j;
            uacc[(size_t)r * 64 + lane] = usA + usB - LN2 * (float)c;
        }
    }
}

// Dense epilogue GEMM: w3 = uacc @ W3b2; agg[nl0[r]] += hB[r] * w3 (consecutive atomics).
__global__ __launch_bounds__(256) void k_node_final(const float* __restrict__ uacc,
                                                    const float* __restrict__ W3b2,
                                                    const ushort* __restrict__ hB,
                                                    const int* __restrict__ nl0,
                                                    float* __restrict__ agg) {
    __shared__ uint w2p[64 * 64];   // 16 KB: packed {hi=col 64+l, lo=col l} bf16
    __shared__ float uL[16][68];    // 4.25 KB, padded rows
    for (int i = TID; i < 4096; i += 256) {
        int k = i >> 6, l = i & 63;
        w2p[i] = ((uint)f2bf(W3b2[k * C + 64 + l]) << 16) | (uint)f2bf(W3b2[k * C + l]);
    }
    const int base = blockIdx.x * 16;
    {
        int i = TID;
        int row = i >> 4, col = (i & 15) << 2;
        float4 v = ((const float4*)uacc)[(size_t)(base + row) * 16 + (i & 15)];
        *(float4*)&uL[row][col] = v;
    }
    __syncthreads();
    const int lane = TID & 63;
    const int wv = TID >> 6;
    #pragma unroll
    for (int j = 0; j < 4; ++j) {
        const int row = wv * 4 + j;
        float o0 = 0.f, o1 = 0.f;
        #pragma unroll 8
        for (int k = 0; k < 64; ++k) {
            float a = uL[row][k];            // wave-uniform broadcast read
            uint wp = w2p[k * 64 + lane];
            o0 = fmaf(a, __uint_as_float(wp << 16), o0);
            o1 = fmaf(a, __uint_as_float(wp & 0xFFFF0000u), o1);
        }
        const int r = base + row;
        const int n0 = nl0[r];
        float h0 = bf2f(hB[(size_t)r * C + lane]);
        float h1 = bf2f(hB[(size_t)r * C + 64 + lane]);
        unsafeAtomicAdd(&agg[(size_t)n0 * C + lane], o0 * h0);
        unsafeAtomicAdd(&agg[(size_t)n0 * C + 64 + lane], o1 * h1);
    }
}

// Final output GEMM (f32 out).
__global__ __launch_bounds__(256) void k_gemm16f(const float* __restrict__ A,
                                                 const float* __restrict__ W,
                                                 float* __restrict__ out, int nrows) {
    __shared__ ushort wB[C * C];
    __shared__ float aL[16][132];
    for (int i = TID; i < C * C / 4; i += 256) {
        float4 w4 = ((const float4*)W)[i];
        ushort4 u = {f2bf(w4.x), f2bf(w4.y), f2bf(w4.z), f2bf(w4.w)};
        ((ushort4*)wB)[i] = u;
    }
    const int base = blockIdx.x * 16;
    for (int i = TID; i < 512; i += 256) {
        int r = base + (i >> 5);
        float4 v = (r < nrows) ? ((const float4*)A)[(size_t)r * 32 + (i & 31)]
                               : (float4){0.f, 0.f, 0.f, 0.f};
        *(float4*)&aL[i >> 5][(i & 31) << 2] = v;
    }
    __syncthreads();
    const int rg = TID >> 4;
    const int c8 = (TID & 15) << 3;
    float acc[8] = {0.f, 0.f, 0.f, 0.f, 0.f, 0.f, 0.f, 0.f};
    #pragma unroll 8
    for (int k = 0; k < C; ++k) {
        float a = aL[rg][k];
        u16x8 wv = *(const u16x8*)&wB[k * C + c8];
        #pragma unroll
        for (int j = 0; j < 8; ++j) acc[j] = fmaf(a, bf2f(wv[j]), acc[j]);
    }
    int r = base + rg;
    if (r < nrows) {
        float4 o0 = {acc[0], acc[1], acc[2], acc[3]};
        float4 o1 = {acc[4], acc[5], acc[6], acc[7]};
        *(float4*)&out[(size_t)r * C + c8] = o0;
        *(float4*)&out[(size_t)r * C + c8 + 4] = o1;
    }
}

extern "C" void kernel_launch(void* const* d_in, const int* in_sizes, int n_in,
                              void* d_out, int out_size, void* d_ws, size_t ws_size,
                              hipStream_t stream) {
    const float* features = (const float*)d_in[0];
    const float* ndist    = (const float*)d_in[1];
    const int*   nlist    = (const int*)d_in[2];
    const int*   tidx     = (const int*)d_in[3];
    const float* angles   = (const float*)d_in[4];
    const float* rij      = (const float*)d_in[5];
    const float* rik      = (const float*)d_in[6];
    const float* W_pre    = (const float*)d_in[7];
    const float* W2b1     = (const float*)d_in[8];
    const float* W2b2     = (const float*)d_in[9];
    const float* W3b1     = (const float*)d_in[10];
    const float* W3b2     = (const float*)d_in[11];
    const float* W_post   = (const float*)d_in[12];
    float* out = (float*)d_out;

    char* w = (char*)d_ws;
    float* agg    = (float*)w;   w += (size_t)NN * C * 4;      // 10.24 MB
    ushort* hB    = (ushort*)w;  w += (size_t)NN * C * 2;      // 5.12 MB
    ushort* lutB  = (ushort*)w;  w += (size_t)LUTN * C * 2;    // 1.05 MB
    int2* eT      = (int2*)w;    w += (size_t)NE * 8;          // 5.12 MB
    int2* tT      = (int2*)w;    w += (size_t)NT * 8;          // 8 MB
    float* uacc   = (float*)w;   w += (size_t)NN * 64 * 4;     // 5.12 MB
    int* t1c      = (int*)w;     w += (size_t)NT * 4;          // 4 MB
    uchar* cntE   = (uchar*)w;   w += (size_t)NBKT * NB2;      // 320 KB
    uchar* cntT   = (uchar*)w;   w += (size_t)NBKT * NB2;
    ushort* baseE = (ushort*)w;  w += (size_t)NBKT * NB2 * 2;  // 640 KB
    ushort* baseT = (ushort*)w;  w += (size_t)NBKT * NB2 * 2;
    int* totEb    = (int*)w;     w += (size_t)NBKT * 4;
    int* totTb    = (int*)w;     w += (size_t)NBKT * 4;
    float2* spLut = (float2*)w;  w += 512 * 8;                 // 4 KB

    const int* nl0 = nlist;
    const int* nl1 = nlist + NE;

    hipLaunchKernelGGL(k_front, dim3(G_GEMM + G_LUT + NB2), dim3(256), 0, stream,
                       features, W_pre, hB, W2b1, W2b2, lutB, spLut,
                       nl0, tidx, cntE, cntT, t1c);
    hipLaunchKernelGGL(k_mid, dim3(G_SCAN), dim3(256), 0, stream,
                       cntE, cntT, baseE, baseT, totEb, totTb);
    hipLaunchKernelGGL(k_bplace, dim3(NB2), dim3(256), 0, stream,
                       nl0, nl1, ndist, t1c, angles, rij, rik,
                       baseE, baseT, totEb, totTb, eT, tT);
    hipLaunchKernelGGL(k_sortcons, dim3(2 * NBKT), dim3(256), 0, stream,
                       eT, tT, totEb, totTb, hB, lutB, W3b1, spLut, agg, uacc);
    hipLaunchKernelGGL(k_node_final, dim3(NN / 16), dim3(256), 0, stream,
                       uacc, W3b2, hB, nl0, agg);
    hipLaunchKernelGGL(k_gemm16f, dim3((NN + 15) / 16), dim3(256), 0, stream,
                       agg, W_post, out, NN);
}